// Round 11
// baseline (484.732 us; speedup 1.0000x reference)
//
#include <hip/hip_runtime.h>
#include <hip/hip_bf16.h>
#include <stdint.h>

#define NN 50000
#define M_PAD 50048                         // padded rows: 391 tiles of 128
#define NE 400000
#define CIN 256
#define KF 320                              // fused layer-0 K: 256 feats + 1 deg col + 63 zeros
#define HID 512
#define COUT 128
#define NG 64
#define SCAN_NB ((NN + 255) / 256)          // 196
#define MT128 (M_PAD / 128)                 // 391
#define GEMM_BLOCKS 512                     // persistent: 2/CU, 64/XCD

typedef short bf16x8 __attribute__((ext_vector_type(8)));
typedef float f32x4 __attribute__((ext_vector_type(4)));
typedef unsigned int u32x2 __attribute__((ext_vector_type(2)));

__device__ inline float bf2f(unsigned short u) {
    union { unsigned int i; float f; } v; v.i = ((unsigned int)u) << 16; return v.f;
}
__device__ inline unsigned short f2bf(float f) {
    union { float f; unsigned int u; } v; v.f = f;
    unsigned int r = v.u + 0x7fffu + ((v.u >> 16) & 1u);
    return (unsigned short)(r >> 16);
}

__device__ inline void async16(const void* g, void* l) {
    __builtin_amdgcn_global_load_lds((const __attribute__((address_space(1))) void*)g,
                                     (__attribute__((address_space(3))) void*)l, 16, 0, 0);
}

// ---------------- small prep kernels ----------------

__global__ void k_f32_to_bf16(const float* __restrict__ in, unsigned short* __restrict__ out, int n4) {
    int i = blockIdx.x * blockDim.x + threadIdx.x;
    if (i < n4) {
        float4 v = ((const float4*)in)[i];
        ushort4 o;
        o.x = f2bf(v.x); o.y = f2bf(v.y); o.z = f2bf(v.z); o.w = f2bf(v.w);
        ((ushort4*)out)[i] = o;
    }
}

// in: [K][N] f32 row-major -> out: [N][K] bf16
__global__ void k_transpose_cvt(const float* __restrict__ in, unsigned short* __restrict__ out, int K, int N) {
    __shared__ float tile[32][33];
    int bx = blockIdx.x * 32, by = blockIdx.y * 32;
    int tx = threadIdx.x & 31, ty = threadIdx.x >> 5; // 256 thr: ty 0..7
    for (int i = 0; i < 32; i += 8)
        tile[ty + i][tx] = in[(size_t)(by + ty + i) * N + bx + tx];
    __syncthreads();
    for (int i = 0; i < 32; i += 8)
        out[(size_t)(bx + ty + i) * K + by + tx] = f2bf(tile[tx][ty + i]);
}

// fused layer-0 weight: WfT[n][k] = (enc_w @ W0)[k][n] for k<256; row 256 = enc_b@W0; rest 0
__global__ void k_fuse_w0(const float* __restrict__ enc_w, const float* __restrict__ enc_b,
                          const float* __restrict__ W0, unsigned short* __restrict__ WfT) {
    int n = blockIdx.x;                 // 0..511
    __shared__ float col[HID];
    for (int j = threadIdx.x; j < HID; j += 256) col[j] = W0[(size_t)j * HID + n];
    __syncthreads();
    int k = threadIdx.x;                // 0..255
    float acc = 0.f;
    for (int j = 0; j < HID; j++) acc += enc_w[(size_t)k * HID + j] * col[j];
    WfT[(size_t)n * KF + k] = f2bf(acc);
    if (k == 0) {
        float v = 0.f;
        for (int j = 0; j < HID; j++) v += enc_b[j] * col[j];
        WfT[(size_t)n * KF + 256] = f2bf(v);
    }
    if (k >= 1 && k < 64) WfT[(size_t)n * KF + 256 + k] = 0;
}

// per-column fused scale/shift for GEMM epilogues (indices 1..4 used)
__global__ void k_affine(const float* __restrict__ enc_b,
                         const float* __restrict__ cb0, const float* __restrict__ bg0, const float* __restrict__ bb0,
                         const float* __restrict__ cb1, const float* __restrict__ bg1, const float* __restrict__ bb1,
                         float* __restrict__ scale, float* __restrict__ shift) {
    int c = threadIdx.x; // 512
    const float inv = 0.9999950000374997f; // 1/sqrt(1+1e-5)
    scale[c] = 1.f; shift[c] = enc_b[c];
    for (int l = 0; l < 2; l++) {
        float s0 = bg0[l * HID + c] * inv;
        scale[(1 + 2 * l) * HID + c] = s0;
        shift[(1 + 2 * l) * HID + c] = cb0[l * HID + c] * s0 + bb0[l * HID + c];
        float s1 = bg1[l * HID + c] * inv;
        scale[(2 + 2 * l) * HID + c] = s1;
        shift[(2 + 2 * l) * HID + c] = cb1[l * HID + c] * s1 + bb1[l * HID + c];
    }
}

// ---------------- CSR build ----------------

__global__ void k_hist(const int* __restrict__ dst, int* __restrict__ indeg, int n) {
    int i = blockIdx.x * blockDim.x + threadIdx.x;
    if (i < n) atomicAdd(&indeg[dst[i]], 1);
}

__global__ void k_scan1(const int* __restrict__ indeg, int* __restrict__ local,
                        int* __restrict__ blocksum, int n) {
    __shared__ int s[256];
    int t = threadIdx.x;
    int i = blockIdx.x * 256 + t;
    int v = (i < n) ? indeg[i] : 0;
    s[t] = v;
    __syncthreads();
    for (int d = 1; d < 256; d <<= 1) {
        int u = (t >= d) ? s[t - d] : 0;
        __syncthreads();
        s[t] += u;
        __syncthreads();
    }
    if (i < n) local[i] = s[t] - v;
    if (t == 255) blocksum[blockIdx.x] = s[255];
}

__global__ void k_scan2(int* __restrict__ blocksum, int nb) {
    __shared__ int s[256];
    int t = threadIdx.x;
    int v = (t < nb) ? blocksum[t] : 0;
    s[t] = v;
    __syncthreads();
    for (int d = 1; d < 256; d <<= 1) {
        int u = (t >= d) ? s[t - d] : 0;
        __syncthreads();
        s[t] += u;
        __syncthreads();
    }
    if (t < nb) blocksum[t] = s[t] - v;
}

__global__ void k_scan3(const int* __restrict__ local, const int* __restrict__ blocksum,
                        const int* __restrict__ indeg, int* __restrict__ off,
                        int* __restrict__ cursor, int n) {
    int i = blockIdx.x * 256 + threadIdx.x;
    if (i < n) {
        int o = local[i] + blocksum[blockIdx.x];
        off[i] = o;
        cursor[i] = o;
        if (i == n - 1) off[n] = o + indeg[i];
    }
}

__global__ void k_fill(const int* __restrict__ src, const int* __restrict__ dst,
                       int* __restrict__ cursor, int* __restrict__ csr, int n) {
    int i = blockIdx.x * blockDim.x + threadIdx.x;
    if (i < n) {
        int p = atomicAdd(&cursor[dst[i]], 1);
        csr[p] = src[i];
    }
}

// ---------------- layer-0 aggregation on RAW 256-dim features + deg column ----------------

__global__ void k_aggregate0(const unsigned short* __restrict__ x, const int* __restrict__ off,
                             const int* __restrict__ csr, unsigned short* __restrict__ z) {
    int wid = (int)((blockIdx.x * blockDim.x + threadIdx.x) >> 6);
    if (wid >= NN) return;
    int lane = threadIdx.x & 63;
    const uint2* xr = (const uint2*)x; // row = 64 uint2 (256 bf16)
    uint2 v = xr[(size_t)wid * 64 + lane];
    float acc[4];
    {
        unsigned short* p = (unsigned short*)&v;
        for (int i = 0; i < 4; i++) acc[i] = bf2f(p[i]);
    }
    int e0 = off[wid], e1 = off[wid + 1];
    int e = e0;
    for (; e + 3 < e1; e += 4) {
        int u0 = csr[e], u1 = csr[e + 1], u2 = csr[e + 2], u3 = csr[e + 3];
        uint2 v0 = xr[(size_t)u0 * 64 + lane];
        uint2 v1 = xr[(size_t)u1 * 64 + lane];
        uint2 v2 = xr[(size_t)u2 * 64 + lane];
        uint2 v3 = xr[(size_t)u3 * 64 + lane];
        unsigned short* p0 = (unsigned short*)&v0;
        unsigned short* p1 = (unsigned short*)&v1;
        unsigned short* p2 = (unsigned short*)&v2;
        unsigned short* p3 = (unsigned short*)&v3;
#pragma unroll
        for (int i = 0; i < 4; i++)
            acc[i] += (bf2f(p0[i]) + bf2f(p1[i])) + (bf2f(p2[i]) + bf2f(p3[i]));
    }
    for (; e < e1; e++) {
        int u = csr[e];
        uint2 vu = xr[(size_t)u * 64 + lane];
        unsigned short* p = (unsigned short*)&vu;
#pragma unroll
        for (int i = 0; i < 4; i++) acc[i] += bf2f(p[i]);
    }
    uint2 o;
    unsigned short* po = (unsigned short*)&o;
    for (int i = 0; i < 4; i++) po[i] = f2bf(acc[i]);
    uint2* zr = (uint2*)z; // row = 80 uint2 (320 bf16)
    zr[(size_t)wid * 80 + lane] = o;
    if (lane < 16) {
        uint2 ex; ex.x = 0; ex.y = 0;
        if (lane == 0) ex.x = (unsigned)f2bf((float)(1 + e1 - e0));
        zr[(size_t)wid * 80 + 64 + lane] = ex;
    }
}

// ---------------- layer-1 aggregation: 512-dim ----------------

__global__ void k_aggregate(const unsigned short* __restrict__ x, const int* __restrict__ off,
                            const int* __restrict__ csr, unsigned short* __restrict__ h) {
    int wid = (int)((blockIdx.x * blockDim.x + threadIdx.x) >> 6);
    if (wid >= NN) return;
    int lane = threadIdx.x & 63;
    const uint4* xr = (const uint4*)x;
    uint4 v = xr[(size_t)wid * 64 + lane];
    float acc[8];
    {
        unsigned short* p = (unsigned short*)&v;
        for (int i = 0; i < 8; i++) acc[i] = bf2f(p[i]);
    }
    int e0 = off[wid], e1 = off[wid + 1];
    int e = e0;
    for (; e + 3 < e1; e += 4) {
        int u0 = csr[e], u1 = csr[e + 1], u2 = csr[e + 2], u3 = csr[e + 3];
        uint4 v0 = xr[(size_t)u0 * 64 + lane];
        uint4 v1 = xr[(size_t)u1 * 64 + lane];
        uint4 v2 = xr[(size_t)u2 * 64 + lane];
        uint4 v3 = xr[(size_t)u3 * 64 + lane];
        unsigned short* p0 = (unsigned short*)&v0;
        unsigned short* p1 = (unsigned short*)&v1;
        unsigned short* p2 = (unsigned short*)&v2;
        unsigned short* p3 = (unsigned short*)&v3;
#pragma unroll
        for (int i = 0; i < 8; i++)
            acc[i] += (bf2f(p0[i]) + bf2f(p1[i])) + (bf2f(p2[i]) + bf2f(p3[i]));
    }
    for (; e < e1; e++) {
        int u = csr[e];
        uint4 vu = xr[(size_t)u * 64 + lane];
        unsigned short* p = (unsigned short*)&vu;
#pragma unroll
        for (int i = 0; i < 8; i++) acc[i] += bf2f(p[i]);
    }
    uint4 o;
    unsigned short* po = (unsigned short*)&o;
    for (int i = 0; i < 8; i++) po[i] = f2bf(acc[i]);
    ((uint4*)h)[(size_t)wid * 64 + lane] = o;
}

// ---------------- bf16 MFMA GEMM: persistent, A-3-deep / B-2-deep counted pipeline ----------
// LDS: A bufs 3x16K @ {0,16K,32K}, B bufs 2x16K @ {48K,64K} = 80 KB exactly -> 2 blocks/CU.
// Static vmcnt (in-order retirement): steady 12; tile-boundary steps 0,1: 28 (12 loads +
// 16 counted asm stores newer than target); last-tile tail 8 -> 0. Staging always writes
// the buffer just read this step (A slot k%3 rotated by NSTEPS%3 per tile; B parity k&1
// ^ bpar, bpar ^= NSTEPS&1 per tile). B panel is block-invariant (nt fixed by slot-stride
// 64) -> cross-tile B restage hits L2. scale/shift live in VGPRs (cols block-invariant).
// T5: s_setprio(1) around MFMA cluster (2 blocks/CU at different phases -> role diversity).

template <int RELU, int NSTEPS>
__global__ __launch_bounds__(256, 2) void k_gemm(const unsigned short* __restrict__ A,
                                                 const unsigned short* __restrict__ WT,
                                                 const float* __restrict__ scale,
                                                 const float* __restrict__ shift,
                                                 unsigned short* __restrict__ out) {
    constexpr int K = NSTEPS * 64;
    __shared__ char lds[81920];
    const int tid = threadIdx.x, w = tid >> 6, lane = tid & 63;
    const int wr = w >> 1, wc = w & 1;
    const int lr = lane & 15, lh = lane >> 4;

    // persistent tile assignment: XCD-chunked, slot-strided (nt invariant per block)
    const int b = blockIdx.x;
    const int xcd = b & 7, slot = b >> 3;
    const int xs = (xcd < 4) ? xcd * 196 : 784 + (xcd - 4) * 195;
    const int xcnt = (xcd < 4) ? 196 : 195;
    const int ntiles = (xcnt - slot + 63) >> 6; // 3 or 4
    int t = xs + slot;
    const int n0 = (t & 3) * 128;               // invariant across this block's tiles

    // scale/shift -> VGPRs (cols fixed per thread), then drain so vmcnt baseline = 0
    f32x4 rsc[4], rsh[4];
#pragma unroll
    for (int nf = 0; nf < 4; nf++) {
        int col = n0 + wc * 64 + nf * 16 + lh * 4;
        rsc[nf] = *(const f32x4*)(scale + col);
        rsh[nf] = *(const f32x4*)(shift + col);
    }
    asm volatile("s_waitcnt vmcnt(0)" ::: "memory");

    // per-thread chunk offsets
    int ldsoff[4], roff[4];
#pragma unroll
    for (int ci = 0; ci < 4; ci++) {
        int cc = w * 4 + ci;
        ldsoff[ci] = cc * 1024;
        roff[ci] = ((cc >> 1) * 16 + lr) * K + (cc & 1) * 32 + lh * 8;
    }

    const int dA = 2048 * K; // next-tile A advance (16 m-tiles of 128 rows)
    const unsigned short* gA[4];
    const unsigned short* gB[4];
    {
        int tile_m = (t >> 2) * 128;
#pragma unroll
        for (int ci = 0; ci < 4; ci++) {
            gA[ci] = A + (size_t)tile_m * K + roff[ci];
            gB[ci] = WT + (size_t)n0 * K + roff[ci];
        }
    }

    int aoff[3] = {0, 16384, 32768};
    int bpar = 0;

    // prologue: A0, B0, A1, B1, A2 (queue order matters for vmcnt math)
#pragma unroll
    for (int ci = 0; ci < 4; ci++) async16(gA[ci], lds + aoff[0] + ldsoff[ci]);
#pragma unroll
    for (int ci = 0; ci < 4; ci++) async16(gB[ci], lds + 49152 + ldsoff[ci]);
#pragma unroll
    for (int ci = 0; ci < 4; ci++) async16(gA[ci] + 64, lds + aoff[1] + ldsoff[ci]);
#pragma unroll
    for (int ci = 0; ci < 4; ci++) async16(gB[ci] + 64, lds + 49152 + 16384 + ldsoff[ci]);
#pragma unroll
    for (int ci = 0; ci < 4; ci++) async16(gA[ci] + 128, lds + aoff[2] + ldsoff[ci]);

    for (int i = 0; i < ntiles; i++) {
        const bool last = (i == ntiles - 1);
        f32x4 acc[4][4];
#pragma unroll
        for (int x = 0; x < 4; x++)
#pragma unroll
            for (int y = 0; y < 4; y++) acc[x][y] = f32x4{0.f, 0.f, 0.f, 0.f};

#pragma unroll
        for (int ks = 0; ks < NSTEPS; ks++) {
            const int ao = aoff[ks % 3];
            const int bo = 49152 + (((ks & 1) ^ bpar) << 14);
            if (i > 0 && ks < 2)                 asm volatile("s_waitcnt vmcnt(28)" ::: "memory");
            else if (last && ks == NSTEPS - 2)   asm volatile("s_waitcnt vmcnt(8)" ::: "memory");
            else if (last && ks == NSTEPS - 1)   asm volatile("s_waitcnt vmcnt(0)" ::: "memory");
            else                                 asm volatile("s_waitcnt vmcnt(12)" ::: "memory");
            __builtin_amdgcn_s_barrier();
            __builtin_amdgcn_sched_barrier(0);
            __builtin_amdgcn_s_setprio(1);
#pragma unroll
            for (int kf = 0; kf < 2; kf++) {
                bf16x8 a[4], bb[4];
#pragma unroll
                for (int mf = 0; mf < 4; mf++)
                    a[mf] = *(const bf16x8*)(lds + ao + ((wr * 4 + mf) * 2 + kf) * 1024 + lane * 16);
#pragma unroll
                for (int nf = 0; nf < 4; nf++)
                    bb[nf] = *(const bf16x8*)(lds + bo + ((wc * 4 + nf) * 2 + kf) * 1024 + lane * 16);
#pragma unroll
                for (int mf = 0; mf < 4; mf++)
#pragma unroll
                    for (int nf = 0; nf < 4; nf++)
                        acc[mf][nf] = __builtin_amdgcn_mfma_f32_16x16x32_bf16(bb[nf], a[mf], acc[mf][nf], 0, 0, 0);
            }
            __builtin_amdgcn_s_setprio(0);
            __builtin_amdgcn_sched_barrier(0);
            __builtin_amdgcn_s_barrier();
            // stage into the buffers just read this step: B target ks+2, A target ks+3
            {
                constexpr int BT = 1; // placeholder to keep structure clear
                (void)BT;
            }
            if (ks + 2 < NSTEPS) {
                int ko = (ks + 2) << 6;
#pragma unroll
                for (int ci = 0; ci < 4; ci++) async16(gB[ci] + ko, lds + bo + ldsoff[ci]);
            } else if (!last) {
                int ko = (ks + 2 - NSTEPS) << 6; // same gB (nt invariant)
#pragma unroll
                for (int ci = 0; ci < 4; ci++) async16(gB[ci] + ko, lds + bo + ldsoff[ci]);
            }
            if (ks + 3 < NSTEPS) {
                int ko = (ks + 3) << 6;
#pragma unroll
                for (int ci = 0; ci < 4; ci++) async16(gA[ci] + ko, lds + ao + ldsoff[ci]);
            } else if (!last) {
                int ko = (ks + 3 - NSTEPS) << 6;
#pragma unroll
                for (int ci = 0; ci < 4; ci++) async16(gA[ci] + dA + ko, lds + ao + ldsoff[ci]);
            }
        }

        // epilogue: exactly 16 counted asm stores; scale/shift from VGPRs
        {
            int tile_m = (t >> 2) * 128;
#pragma unroll
            for (int nf = 0; nf < 4; nf++) {
                int col = n0 + wc * 64 + nf * 16 + lh * 4;
#pragma unroll
                for (int mf = 0; mf < 4; mf++) {
                    int row = tile_m + wr * 64 + mf * 16 + lr;
                    float y0 = acc[mf][nf][0] * rsc[nf][0] + rsh[nf][0];
                    float y1 = acc[mf][nf][1] * rsc[nf][1] + rsh[nf][1];
                    float y2 = acc[mf][nf][2] * rsc[nf][2] + rsh[nf][2];
                    float y3 = acc[mf][nf][3] * rsc[nf][3] + rsh[nf][3];
                    if (RELU) {
                        y0 = fmaxf(y0, 0.f); y1 = fmaxf(y1, 0.f);
                        y2 = fmaxf(y2, 0.f); y3 = fmaxf(y3, 0.f);
                    }
                    u32x2 pd;
                    pd[0] = (unsigned)f2bf(y0) | ((unsigned)f2bf(y1) << 16);
                    pd[1] = (unsigned)f2bf(y2) | ((unsigned)f2bf(y3) << 16);
                    unsigned long long ap = (unsigned long long)(out + (size_t)row * HID + col);
                    asm volatile("global_store_dwordx2 %0, %1, off" :: "v"(ap), "v"(pd) : "memory");
                }
            }
        }

        if (!last) {
#pragma unroll
            for (int ci = 0; ci < 4; ci++) gA[ci] += dA;
            t += 64;
            // rotate A slots by NSTEPS%3; flip B parity by NSTEPS&1
            constexpr int R = NSTEPS % 3;
            if (R != 0) {
                int a0 = aoff[0], a1 = aoff[1], a2 = aoff[2];
                if (R == 2) { aoff[0] = a2; aoff[1] = a0; aoff[2] = a1; }
                else        { aoff[0] = a1; aoff[1] = a2; aoff[2] = a0; }
            }
            bpar ^= (NSTEPS & 1);
        }
    }
}

// ---------------- pooling + folded tail ----------------

__global__ void k_bounds(const int* __restrict__ batch, int* __restrict__ bounds) {
    int t = threadIdx.x;
    if (t <= NG) {
        int lo = 0, hi = NN;
        while (lo < hi) { int mid = (lo + hi) >> 1; if (batch[mid] < t) lo = mid + 1; else hi = mid; }
        bounds[t] = lo;
    }
}

__global__ void k_pool(const unsigned short* __restrict__ x, const int* __restrict__ bounds,
                       float* __restrict__ pooled) {
    int g = blockIdx.x, s = blockIdx.y, t = threadIdx.x; // 512 thr
    int b0 = bounds[g], b1 = bounds[g + 1];
    int len = b1 - b0;
    int r0 = b0 + (int)((long long)len * s / 8);
    int r1 = b0 + (int)((long long)len * (s + 1) / 8);
    float acc = 0.f;
    for (int r = r0; r < r1; r++) acc += bf2f(x[(size_t)r * HID + t]);
    if (r1 > r0) atomicAdd(&pooled[g * HID + t], acc);
}

__global__ void k_tailgemm(const float* __restrict__ pooledSum, const int* __restrict__ bounds,
                           const float* __restrict__ W1, const float* __restrict__ scale,
                           const float* __restrict__ shift, float* __restrict__ xfp) {
    int g = blockIdx.x, t = threadIdx.x; // 512
    __shared__ float row[HID];
    int cnt = bounds[g + 1] - bounds[g];
    float invc = 1.f / fmaxf((float)cnt, 1.f);
    row[t] = pooledSum[g * HID + t] * invc;
    __syncthreads();
    float acc = 0.f;
    for (int k = 0; k < HID; k++) acc += row[k] * W1[(size_t)k * HID + t];
    xfp[g * HID + t] = acc * scale[t] + shift[t];
}

__global__ void k_head1(const float* __restrict__ xfp, const float* __restrict__ lin_w,
                        const float* __restrict__ lin_b, float* __restrict__ gout) {
    int g = blockIdx.x, t = threadIdx.x; // 512
    __shared__ float row[HID];
    row[t] = xfp[g * HID + t];
    __syncthreads();
    float acc = lin_b[t];
    for (int k = 0; k < HID; k++) acc += row[k] * lin_w[(size_t)k * HID + t];
    gout[g * HID + t] = 0.5f * acc * (1.f + erff(acc * 0.7071067811865475f));
}

__global__ void k_head2(const float* __restrict__ gbuf, const float* __restrict__ clf_w,
                        const float* __restrict__ clf_b, float* __restrict__ out) {
    int g = blockIdx.x, t = threadIdx.x; // 128
    __shared__ float row[HID];
    for (int k = t; k < HID; k += 128) row[k] = gbuf[g * HID + k];
    __syncthreads();
    float acc = clf_b[t];
    for (int k = 0; k < HID; k++) acc += row[k] * clf_w[(size_t)k * COUT + t];
    out[g * COUT + t] = acc;
}

// ---------------- launch ----------------

extern "C" void kernel_launch(void* const* d_in, const int* in_sizes, int n_in,
                              void* d_out, int out_size, void* d_ws, size_t ws_size,
                              hipStream_t stream) {
    const float* x_f32   = (const float*)d_in[0];
    const int*   ei      = (const int*)d_in[1];
    const int*   batch   = (const int*)d_in[2];
    const float* enc_w   = (const float*)d_in[3];
    const float* enc_b   = (const float*)d_in[4];
    const float* conv_w0 = (const float*)d_in[5];
    const float* conv_b0 = (const float*)d_in[6];
    const float* bn0_g   = (const float*)d_in[7];
    const float* bn0_b   = (const float*)d_in[8];
    const float* conv_w1 = (const float*)d_in[9];
    const float* conv_b1 = (const float*)d_in[10];
    const float* bn1_g   = (const float*)d_in[11];
    const float* bn1_b   = (const float*)d_in[12];
    const float* lin_w   = (const float*)d_in[13];
    const float* lin_b   = (const float*)d_in[14];
    const float* clf_w   = (const float*)d_in[15];
    const float* clf_b   = (const float*)d_in[16];
    const int* srcp = ei;
    const int* dstp = ei + NE;

    char* ws = (char*)d_ws;
    size_t o = 0;
    auto alloc = [&](size_t b) { size_t r = o; o += (b + 255) & ~(size_t)255; return r; };
    unsigned short* buf0 = (unsigned short*)(ws + alloc((size_t)M_PAD * HID * 2));
    unsigned short* buf1 = (unsigned short*)(ws + alloc((size_t)M_PAD * HID * 2));
    unsigned short* buf2 = (unsigned short*)(ws + alloc((size_t)M_PAD * HID * 2));
    unsigned short* xbf  = buf0;  // alias: raw bf16 feats [NN][256]; dead after k_aggregate0
    unsigned short* zbuf = buf2;  // alias: agg0 output [M_PAD][320]; dead after l0 GEMM
    unsigned short* WfT  = (unsigned short*)(ws + alloc((size_t)HID * KF * 2));
    unsigned short* c0T  = (unsigned short*)(ws + alloc((size_t)HID * HID * 2)); // conv_w0[1]^T
    unsigned short* c1T  = (unsigned short*)(ws + alloc((size_t)HID * HID * 2)); // conv_w1[0]^T
    float* aff_scale = (float*)(ws + alloc(5 * HID * 4));
    float* aff_shift = (float*)(ws + alloc(5 * HID * 4));
    int* indeg  = (int*)(ws + alloc((size_t)NN * 4));
    int* off    = (int*)(ws + alloc((size_t)(NN + 1) * 4));
    int* cursor = (int*)(ws + alloc((size_t)NN * 4));
    int* csr    = (int*)(ws + alloc((size_t)NE * 4));
    int* scan_local = (int*)(ws + alloc((size_t)NN * 4));
    int* scan_bsum  = (int*)(ws + alloc((size_t)256 * 4));
    int* bounds = (int*)(ws + alloc((size_t)(NG + 1) * 4));
    float* pooledSum = (float*)(ws + alloc((size_t)NG * HID * 4));
    float* xfp       = (float*)(ws + alloc((size_t)NG * HID * 4));
    float* gbuf      = (float*)(ws + alloc((size_t)NG * HID * 4));
    (void)ws_size; (void)n_in; (void)in_sizes; (void)out_size;

    hipMemsetAsync(indeg, 0, (size_t)NN * 4, stream);
    hipMemsetAsync(pooledSum, 0, (size_t)NG * HID * 4, stream);

    // weight prep
    k_f32_to_bf16<<<(NN * CIN / 4 + 255) / 256, 256, 0, stream>>>(x_f32, xbf, NN * CIN / 4);
    k_fuse_w0<<<HID, 256, 0, stream>>>(enc_w, enc_b, conv_w0, WfT);
    k_transpose_cvt<<<dim3(16, 16), 256, 0, stream>>>(conv_w0 + HID * HID, c0T, HID, HID);
    k_transpose_cvt<<<dim3(16, 16), 256, 0, stream>>>(conv_w1, c1T, HID, HID);
    k_affine<<<1, 512, 0, stream>>>(enc_b, conv_b0, bn0_g, bn0_b, conv_b1, bn1_g, bn1_b,
                                    aff_scale, aff_shift);

    // CSR (hierarchical scan)
    k_hist<<<(NE + 255) / 256, 256, 0, stream>>>(dstp, indeg, NE);
    k_scan1<<<SCAN_NB, 256, 0, stream>>>(indeg, scan_local, scan_bsum, NN);
    k_scan2<<<1, 256, 0, stream>>>(scan_bsum, SCAN_NB);
    k_scan3<<<SCAN_NB, 256, 0, stream>>>(scan_local, scan_bsum, indeg, off, cursor, NN);
    k_fill<<<(NE + 255) / 256, 256, 0, stream>>>(srcp, dstp, cursor, csr, NE);
    k_bounds<<<1, 128, 0, stream>>>(batch, bounds);

    // layer 0 (folded): agg raw 256-dim feats (+deg col) -> K=320 GEMM -> K=512 GEMM
    k_aggregate0<<<(NN * 64) / 256, 256, 0, stream>>>(xbf, off, csr, zbuf);
    k_gemm<1, KF / 64><<<GEMM_BLOCKS, 256, 0, stream>>>(zbuf, WfT,
                                                        aff_scale + 1 * HID, aff_shift + 1 * HID, buf0);
    k_gemm<1, HID / 64><<<GEMM_BLOCKS, 256, 0, stream>>>(buf0, c1T,
                                                         aff_scale + 2 * HID, aff_shift + 2 * HID, buf2);

    // layer 1: agg -> GEMM (bn0[1]+relu); final GEMM folded into tail
    k_aggregate<<<(NN * 64) / 256, 256, 0, stream>>>(buf2, off, csr, buf1);
    k_gemm<1, HID / 64><<<GEMM_BLOCKS, 256, 0, stream>>>(buf1, c0T,
                                                         aff_scale + 3 * HID, aff_shift + 3 * HID, buf2);

    // tail: pool h1, tiny fp32 GEMM + affine, then heads
    k_pool<<<dim3(NG, 8), 512, 0, stream>>>(buf2, bounds, pooledSum);
    k_tailgemm<<<NG, 512, 0, stream>>>(pooledSum, bounds, conv_w1 + HID * HID,
                                       aff_scale + 4 * HID, aff_shift + 4 * HID, xfp);
    k_head1<<<NG, 512, 0, stream>>>(xfp, lin_w, lin_b, gbuf);
    k_head2<<<NG, 128, 0, stream>>>(gbuf, clf_w, clf_b, (float*)d_out);
}

// Round 12
// 453.499 us; speedup vs baseline: 1.0689x; 1.0689x over previous
//
#include <hip/hip_runtime.h>
#include <hip/hip_bf16.h>
#include <stdint.h>

#define NN 50000
#define M_PAD 50176                         // 196 tiles of 256 rows
#define NE 400000
#define CIN 256
#define KF 320                              // fused layer-0 K: 256 feats + 1 deg col + 63 zeros
#define HID 512
#define COUT 128
#define NG 64
#define SCAN_NB ((NN + 255) / 256)          // 196
#define GEMM_NWG 392                        // 196 mt x 2 nt = 392 = 8*49

typedef short bf16x8 __attribute__((ext_vector_type(8)));
typedef float f32x4 __attribute__((ext_vector_type(4)));

__device__ inline float bf2f(unsigned short u) {
    union { unsigned int i; float f; } v; v.i = ((unsigned int)u) << 16; return v.f;
}
__device__ inline unsigned short f2bf(float f) {
    union { float f; unsigned int u; } v; v.f = f;
    unsigned int r = v.u + 0x7fffu + ((v.u >> 16) & 1u);
    return (unsigned short)(r >> 16);
}

__device__ inline void async16(const void* g, void* l) {
    __builtin_amdgcn_global_load_lds((const __attribute__((address_space(1))) void*)g,
                                     (__attribute__((address_space(3))) void*)l, 16, 0, 0);
}

// ---------------- small prep kernels ----------------

__global__ void k_f32_to_bf16(const float* __restrict__ in, unsigned short* __restrict__ out, int n4) {
    int i = blockIdx.x * blockDim.x + threadIdx.x;
    if (i < n4) {
        float4 v = ((const float4*)in)[i];
        ushort4 o;
        o.x = f2bf(v.x); o.y = f2bf(v.y); o.z = f2bf(v.z); o.w = f2bf(v.w);
        ((ushort4*)out)[i] = o;
    }
}

// in: [K][N] f32 row-major -> out: [N][K] bf16
__global__ void k_transpose_cvt(const float* __restrict__ in, unsigned short* __restrict__ out, int K, int N) {
    __shared__ float tile[32][33];
    int bx = blockIdx.x * 32, by = blockIdx.y * 32;
    int tx = threadIdx.x & 31, ty = threadIdx.x >> 5; // 256 thr: ty 0..7
    for (int i = 0; i < 32; i += 8)
        tile[ty + i][tx] = in[(size_t)(by + ty + i) * N + bx + tx];
    __syncthreads();
    for (int i = 0; i < 32; i += 8)
        out[(size_t)(bx + ty + i) * K + by + tx] = f2bf(tile[tx][ty + i]);
}

// fused layer-0 weight: WfT[n][k] = (enc_w @ W0)[k][n] for k<256; row 256 = enc_b@W0; rest 0
__global__ void k_fuse_w0(const float* __restrict__ enc_w, const float* __restrict__ enc_b,
                          const float* __restrict__ W0, unsigned short* __restrict__ WfT) {
    int n = blockIdx.x;                 // 0..511
    __shared__ float col[HID];
    for (int j = threadIdx.x; j < HID; j += 256) col[j] = W0[(size_t)j * HID + n];
    __syncthreads();
    int k = threadIdx.x;                // 0..255
    float acc = 0.f;
    for (int j = 0; j < HID; j++) acc += enc_w[(size_t)k * HID + j] * col[j];
    WfT[(size_t)n * KF + k] = f2bf(acc);
    if (k == 0) {
        float v = 0.f;
        for (int j = 0; j < HID; j++) v += enc_b[j] * col[j];
        WfT[(size_t)n * KF + 256] = f2bf(v);
    }
    if (k >= 1 && k < 64) WfT[(size_t)n * KF + 256 + k] = 0;
}

// per-column fused scale/shift for GEMM epilogues (indices 1..4 used)
__global__ void k_affine(const float* __restrict__ enc_b,
                         const float* __restrict__ cb0, const float* __restrict__ bg0, const float* __restrict__ bb0,
                         const float* __restrict__ cb1, const float* __restrict__ bg1, const float* __restrict__ bb1,
                         float* __restrict__ scale, float* __restrict__ shift) {
    int c = threadIdx.x; // 512
    const float inv = 0.9999950000374997f; // 1/sqrt(1+1e-5)
    scale[c] = 1.f; shift[c] = enc_b[c];
    for (int l = 0; l < 2; l++) {
        float s0 = bg0[l * HID + c] * inv;
        scale[(1 + 2 * l) * HID + c] = s0;
        shift[(1 + 2 * l) * HID + c] = cb0[l * HID + c] * s0 + bb0[l * HID + c];
        float s1 = bg1[l * HID + c] * inv;
        scale[(2 + 2 * l) * HID + c] = s1;
        shift[(2 + 2 * l) * HID + c] = cb1[l * HID + c] * s1 + bb1[l * HID + c];
    }
}

// ---------------- CSR build ----------------

__global__ void k_hist(const int* __restrict__ dst, int* __restrict__ indeg, int n) {
    int i = blockIdx.x * blockDim.x + threadIdx.x;
    if (i < n) atomicAdd(&indeg[dst[i]], 1);
}

__global__ void k_scan1(const int* __restrict__ indeg, int* __restrict__ local,
                        int* __restrict__ blocksum, int n) {
    __shared__ int s[256];
    int t = threadIdx.x;
    int i = blockIdx.x * 256 + t;
    int v = (i < n) ? indeg[i] : 0;
    s[t] = v;
    __syncthreads();
    for (int d = 1; d < 256; d <<= 1) {
        int u = (t >= d) ? s[t - d] : 0;
        __syncthreads();
        s[t] += u;
        __syncthreads();
    }
    if (i < n) local[i] = s[t] - v;
    if (t == 255) blocksum[blockIdx.x] = s[255];
}

__global__ void k_scan2(int* __restrict__ blocksum, int nb) {
    __shared__ int s[256];
    int t = threadIdx.x;
    int v = (t < nb) ? blocksum[t] : 0;
    s[t] = v;
    __syncthreads();
    for (int d = 1; d < 256; d <<= 1) {
        int u = (t >= d) ? s[t - d] : 0;
        __syncthreads();
        s[t] += u;
        __syncthreads();
    }
    if (t < nb) blocksum[t] = s[t] - v;
}

__global__ void k_scan3(const int* __restrict__ local, const int* __restrict__ blocksum,
                        const int* __restrict__ indeg, int* __restrict__ off,
                        int* __restrict__ cursor, int n) {
    int i = blockIdx.x * 256 + threadIdx.x;
    if (i < n) {
        int o = local[i] + blocksum[blockIdx.x];
        off[i] = o;
        cursor[i] = o;
        if (i == n - 1) off[n] = o + indeg[i];
    }
}

__global__ void k_fill(const int* __restrict__ src, const int* __restrict__ dst,
                       int* __restrict__ cursor, int* __restrict__ csr, int n) {
    int i = blockIdx.x * blockDim.x + threadIdx.x;
    if (i < n) {
        int p = atomicAdd(&cursor[dst[i]], 1);
        csr[p] = src[i];
    }
}

// ---------------- layer-0 aggregation on RAW 256-dim features + deg column ----------------

__global__ void k_aggregate0(const unsigned short* __restrict__ x, const int* __restrict__ off,
                             const int* __restrict__ csr, unsigned short* __restrict__ z) {
    int wid = (int)((blockIdx.x * blockDim.x + threadIdx.x) >> 6);
    if (wid >= NN) return;
    int lane = threadIdx.x & 63;
    const uint2* xr = (const uint2*)x; // row = 64 uint2 (256 bf16)
    uint2 v = xr[(size_t)wid * 64 + lane];
    float acc[4];
    {
        unsigned short* p = (unsigned short*)&v;
        for (int i = 0; i < 4; i++) acc[i] = bf2f(p[i]);
    }
    int e0 = off[wid], e1 = off[wid + 1];
    int e = e0;
    for (; e + 3 < e1; e += 4) {
        int u0 = csr[e], u1 = csr[e + 1], u2 = csr[e + 2], u3 = csr[e + 3];
        uint2 v0 = xr[(size_t)u0 * 64 + lane];
        uint2 v1 = xr[(size_t)u1 * 64 + lane];
        uint2 v2 = xr[(size_t)u2 * 64 + lane];
        uint2 v3 = xr[(size_t)u3 * 64 + lane];
        unsigned short* p0 = (unsigned short*)&v0;
        unsigned short* p1 = (unsigned short*)&v1;
        unsigned short* p2 = (unsigned short*)&v2;
        unsigned short* p3 = (unsigned short*)&v3;
#pragma unroll
        for (int i = 0; i < 4; i++)
            acc[i] += (bf2f(p0[i]) + bf2f(p1[i])) + (bf2f(p2[i]) + bf2f(p3[i]));
    }
    for (; e < e1; e++) {
        int u = csr[e];
        uint2 vu = xr[(size_t)u * 64 + lane];
        unsigned short* p = (unsigned short*)&vu;
#pragma unroll
        for (int i = 0; i < 4; i++) acc[i] += bf2f(p[i]);
    }
    uint2 o;
    unsigned short* po = (unsigned short*)&o;
    for (int i = 0; i < 4; i++) po[i] = f2bf(acc[i]);
    uint2* zr = (uint2*)z; // row = 80 uint2 (320 bf16)
    zr[(size_t)wid * 80 + lane] = o;
    if (lane < 16) {
        uint2 ex; ex.x = 0; ex.y = 0;
        if (lane == 0) ex.x = (unsigned)f2bf((float)(1 + e1 - e0));
        zr[(size_t)wid * 80 + 64 + lane] = ex;
    }
}

// ---------------- layer-1 aggregation: 512-dim ----------------

__global__ void k_aggregate(const unsigned short* __restrict__ x, const int* __restrict__ off,
                            const int* __restrict__ csr, unsigned short* __restrict__ h) {
    int wid = (int)((blockIdx.x * blockDim.x + threadIdx.x) >> 6);
    if (wid >= NN) return;
    int lane = threadIdx.x & 63;
    const uint4* xr = (const uint4*)x;
    uint4 v = xr[(size_t)wid * 64 + lane];
    float acc[8];
    {
        unsigned short* p = (unsigned short*)&v;
        for (int i = 0; i < 8; i++) acc[i] = bf2f(p[i]);
    }
    int e0 = off[wid], e1 = off[wid + 1];
    int e = e0;
    for (; e + 3 < e1; e += 4) {
        int u0 = csr[e], u1 = csr[e + 1], u2 = csr[e + 2], u3 = csr[e + 3];
        uint4 v0 = xr[(size_t)u0 * 64 + lane];
        uint4 v1 = xr[(size_t)u1 * 64 + lane];
        uint4 v2 = xr[(size_t)u2 * 64 + lane];
        uint4 v3 = xr[(size_t)u3 * 64 + lane];
        unsigned short* p0 = (unsigned short*)&v0;
        unsigned short* p1 = (unsigned short*)&v1;
        unsigned short* p2 = (unsigned short*)&v2;
        unsigned short* p3 = (unsigned short*)&v3;
#pragma unroll
        for (int i = 0; i < 8; i++)
            acc[i] += (bf2f(p0[i]) + bf2f(p1[i])) + (bf2f(p2[i]) + bf2f(p3[i]));
    }
    for (; e < e1; e++) {
        int u = csr[e];
        uint4 vu = xr[(size_t)u * 64 + lane];
        unsigned short* p = (unsigned short*)&vu;
#pragma unroll
        for (int i = 0; i < 8; i++) acc[i] += bf2f(p[i]);
    }
    uint4 o;
    unsigned short* po = (unsigned short*)&o;
    for (int i = 0; i < 8; i++) po[i] = f2bf(acc[i]);
    ((uint4*)h)[(size_t)wid * 64 + lane] = o;
}

// ---------------- bf16 MFMA GEMM: BM=256 x BN=256, 8 waves, counted-vmcnt ----------------
// Wave w: wr=w>>2 (rows wr*128, 8 m-frags), wc=w&3 (cols wc*64, 4 n-frags) -> per wave
// per K-step: 24 ds_read_b128 / 64 MFMA (2.7x better ratio than 128^2) and staged bytes
// per GEMM halve. LDS 128 KB = 2 dbuf x (A 32K + B 32K); 1 block/CU, 2 waves/SIMD.
// R8-verified counted-vmcnt skeleton: prologue stages steps 0-1; steady wait vmcnt(8);
// stage ks+2 after read-barrier; final vmcnt(0). Grid 392 = 8*49, XCD-chunked swizzle
// (adjacent wgids share one A-panel on one XCD). Transposed-output packed epilogue.

template <int RELU, int NSTEPS>
__global__ __launch_bounds__(512, 2) void k_gemm(const unsigned short* __restrict__ A,
                                                 const unsigned short* __restrict__ WT,
                                                 const float* __restrict__ scale,
                                                 const float* __restrict__ shift,
                                                 unsigned short* __restrict__ out) {
    constexpr int K = NSTEPS * 64;
    __shared__ char lds[131072];
    const int tid = threadIdx.x, w = tid >> 6, lane = tid & 63;
    const int wr = w >> 2, wc = w & 3;
    const int lr = lane & 15, lh = lane >> 4;

    // bijective XCD swizzle for 392 = 8*49; wgid pairs (nt 0/1) share mt
    int orig = blockIdx.x;
    int wgid = (orig & 7) * 49 + (orig >> 3);
    int tile_m = (wgid >> 1) * 256;
    int n0 = (wgid & 1) * 256;

    // staging: 4 A-chunks + 4 B-chunks per thread (32 chunks of 1 KB each side)
    const unsigned short* gA[4];
    const unsigned short* gB[4];
    int ldsoff[4];
#pragma unroll
    for (int ci = 0; ci < 4; ci++) {
        int c = w * 4 + ci;               // 0..31: f = c>>1 (16-row/col frag), kf = c&1
        int f = c >> 1, kf = c & 1;
        ldsoff[ci] = c * 1024;
        gA[ci] = A + (size_t)(tile_m + f * 16 + lr) * K + kf * 32 + lh * 8;
        gB[ci] = WT + (size_t)(n0 + f * 16 + lr) * K + kf * 32 + lh * 8;
    }

    f32x4 acc[8][4];
#pragma unroll
    for (int x = 0; x < 8; x++)
#pragma unroll
        for (int y = 0; y < 4; y++) acc[x][y] = f32x4{0.f, 0.f, 0.f, 0.f};

    // prologue: stage steps 0,1 (A then B each; 16 loads in flight per thread)
#pragma unroll
    for (int ci = 0; ci < 4; ci++) async16(gA[ci], lds + ldsoff[ci]);
#pragma unroll
    for (int ci = 0; ci < 4; ci++) async16(gB[ci], lds + 32768 + ldsoff[ci]);
#pragma unroll
    for (int ci = 0; ci < 4; ci++) async16(gA[ci] + 64, lds + 65536 + ldsoff[ci]);
#pragma unroll
    for (int ci = 0; ci < 4; ci++) async16(gB[ci] + 64, lds + 65536 + 32768 + ldsoff[ci]);

#pragma unroll
    for (int ks = 0; ks < NSTEPS; ks++) {
        const int cur = (ks & 1) << 16;
        if (ks < NSTEPS - 1) asm volatile("s_waitcnt vmcnt(8)" ::: "memory");
        else                 asm volatile("s_waitcnt vmcnt(0)" ::: "memory");
        __builtin_amdgcn_s_barrier();
        __builtin_amdgcn_sched_barrier(0);
#pragma unroll
        for (int kf = 0; kf < 2; kf++) {
            bf16x8 a[8], bb[4];
#pragma unroll
            for (int mf = 0; mf < 8; mf++)
                a[mf] = *(const bf16x8*)(lds + cur + ((wr * 8 + mf) * 2 + kf) * 1024 + lane * 16);
#pragma unroll
            for (int nf = 0; nf < 4; nf++)
                bb[nf] = *(const bf16x8*)(lds + cur + 32768 + ((wc * 4 + nf) * 2 + kf) * 1024 + lane * 16);
#pragma unroll
            for (int mf = 0; mf < 8; mf++)
#pragma unroll
                for (int nf = 0; nf < 4; nf++)
                    acc[mf][nf] = __builtin_amdgcn_mfma_f32_16x16x32_bf16(bb[nf], a[mf], acc[mf][nf], 0, 0, 0);
        }
        __builtin_amdgcn_sched_barrier(0);
        __builtin_amdgcn_s_barrier();
        if (ks + 2 < NSTEPS) {            // stage step ks+2 into the buffer just read
            int ko = (ks + 2) << 6;
#pragma unroll
            for (int ci = 0; ci < 4; ci++) async16(gA[ci] + ko, lds + cur + ldsoff[ci]);
#pragma unroll
            for (int ci = 0; ci < 4; ci++) async16(gB[ci] + ko, lds + cur + 32768 + ldsoff[ci]);
        }
    }

    // epilogue (transposed acc): row = M from lr, 4 contiguous N-cols from lh*4
#pragma unroll
    for (int nf = 0; nf < 4; nf++) {
        int col = n0 + wc * 64 + nf * 16 + lh * 4;
        float4 sc = *(const float4*)&scale[col];
        float4 sh = *(const float4*)&shift[col];
#pragma unroll
        for (int mf = 0; mf < 8; mf++) {
            int row = tile_m + wr * 128 + mf * 16 + lr;
            float y0 = acc[mf][nf][0] * sc.x + sh.x;
            float y1 = acc[mf][nf][1] * sc.y + sh.y;
            float y2 = acc[mf][nf][2] * sc.z + sh.z;
            float y3 = acc[mf][nf][3] * sc.w + sh.w;
            if (RELU) {
                y0 = fmaxf(y0, 0.f); y1 = fmaxf(y1, 0.f);
                y2 = fmaxf(y2, 0.f); y3 = fmaxf(y3, 0.f);
            }
            ushort4 pk;
            pk.x = f2bf(y0); pk.y = f2bf(y1); pk.z = f2bf(y2); pk.w = f2bf(y3);
            *(ushort4*)(out + (size_t)row * HID + col) = pk;
        }
    }
}

// ---------------- pooling + folded tail ----------------

__global__ void k_bounds(const int* __restrict__ batch, int* __restrict__ bounds) {
    int t = threadIdx.x;
    if (t <= NG) {
        int lo = 0, hi = NN;
        while (lo < hi) { int mid = (lo + hi) >> 1; if (batch[mid] < t) lo = mid + 1; else hi = mid; }
        bounds[t] = lo;
    }
}

__global__ void k_pool(const unsigned short* __restrict__ x, const int* __restrict__ bounds,
                       float* __restrict__ pooled) {
    int g = blockIdx.x, s = blockIdx.y, t = threadIdx.x; // 512 thr
    int b0 = bounds[g], b1 = bounds[g + 1];
    int len = b1 - b0;
    int r0 = b0 + (int)((long long)len * s / 8);
    int r1 = b0 + (int)((long long)len * (s + 1) / 8);
    float acc = 0.f;
    for (int r = r0; r < r1; r++) acc += bf2f(x[(size_t)r * HID + t]);
    if (r1 > r0) atomicAdd(&pooled[g * HID + t], acc);
}

__global__ void k_tailgemm(const float* __restrict__ pooledSum, const int* __restrict__ bounds,
                           const float* __restrict__ W1, const float* __restrict__ scale,
                           const float* __restrict__ shift, float* __restrict__ xfp) {
    int g = blockIdx.x, t = threadIdx.x; // 512
    __shared__ float row[HID];
    int cnt = bounds[g + 1] - bounds[g];
    float invc = 1.f / fmaxf((float)cnt, 1.f);
    row[t] = pooledSum[g * HID + t] * invc;
    __syncthreads();
    float acc = 0.f;
    for (int k = 0; k < HID; k++) acc += row[k] * W1[(size_t)k * HID + t];
    xfp[g * HID + t] = acc * scale[t] + shift[t];
}

__global__ void k_head1(const float* __restrict__ xfp, const float* __restrict__ lin_w,
                        const float* __restrict__ lin_b, float* __restrict__ gout) {
    int g = blockIdx.x, t = threadIdx.x; // 512
    __shared__ float row[HID];
    row[t] = xfp[g * HID + t];
    __syncthreads();
    float acc = lin_b[t];
    for (int k = 0; k < HID; k++) acc += row[k] * lin_w[(size_t)k * HID + t];
    gout[g * HID + t] = 0.5f * acc * (1.f + erff(acc * 0.7071067811865475f));
}

__global__ void k_head2(const float* __restrict__ gbuf, const float* __restrict__ clf_w,
                        const float* __restrict__ clf_b, float* __restrict__ out) {
    int g = blockIdx.x, t = threadIdx.x; // 128
    __shared__ float row[HID];
    for (int k = t; k < HID; k += 128) row[k] = gbuf[g * HID + k];
    __syncthreads();
    float acc = clf_b[t];
    for (int k = 0; k < HID; k++) acc += row[k] * clf_w[(size_t)k * COUT + t];
    out[g * COUT + t] = acc;
}

// ---------------- launch ----------------

extern "C" void kernel_launch(void* const* d_in, const int* in_sizes, int n_in,
                              void* d_out, int out_size, void* d_ws, size_t ws_size,
                              hipStream_t stream) {
    const float* x_f32   = (const float*)d_in[0];
    const int*   ei      = (const int*)d_in[1];
    const int*   batch   = (const int*)d_in[2];
    const float* enc_w   = (const float*)d_in[3];
    const float* enc_b   = (const float*)d_in[4];
    const float* conv_w0 = (const float*)d_in[5];
    const float* conv_b0 = (const float*)d_in[6];
    const float* bn0_g   = (const float*)d_in[7];
    const float* bn0_b   = (const float*)d_in[8];
    const float* conv_w1 = (const float*)d_in[9];
    const float* conv_b1 = (const float*)d_in[10];
    const float* bn1_g   = (const float*)d_in[11];
    const float* bn1_b   = (const float*)d_in[12];
    const float* lin_w   = (const float*)d_in[13];
    const float* lin_b   = (const float*)d_in[14];
    const float* clf_w   = (const float*)d_in[15];
    const float* clf_b   = (const float*)d_in[16];
    const int* srcp = ei;
    const int* dstp = ei + NE;

    char* ws = (char*)d_ws;
    size_t o = 0;
    auto alloc = [&](size_t b) { size_t r = o; o += (b + 255) & ~(size_t)255; return r; };
    unsigned short* buf0 = (unsigned short*)(ws + alloc((size_t)M_PAD * HID * 2));
    unsigned short* buf1 = (unsigned short*)(ws + alloc((size_t)M_PAD * HID * 2));
    unsigned short* buf2 = (unsigned short*)(ws + alloc((size_t)M_PAD * HID * 2));
    unsigned short* xbf  = buf0;  // alias: raw bf16 feats [NN][256]; dead after k_aggregate0
    unsigned short* zbuf = buf2;  // alias: agg0 output [M_PAD][320]; dead after l0 GEMM
    unsigned short* WfT  = (unsigned short*)(ws + alloc((size_t)HID * KF * 2));
    unsigned short* c0T  = (unsigned short*)(ws + alloc((size_t)HID * HID * 2)); // conv_w0[1]^T
    unsigned short* c1T  = (unsigned short*)(ws + alloc((size_t)HID * HID * 2)); // conv_w1[0]^T
    float* aff_scale = (float*)(ws + alloc(5 * HID * 4));
    float* aff_shift = (float*)(ws + alloc(5 * HID * 4));
    int* indeg  = (int*)(ws + alloc((size_t)NN * 4));
    int* off    = (int*)(ws + alloc((size_t)(NN + 1) * 4));
    int* cursor = (int*)(ws + alloc((size_t)NN * 4));
    int* csr    = (int*)(ws + alloc((size_t)NE * 4));
    int* scan_local = (int*)(ws + alloc((size_t)NN * 4));
    int* scan_bsum  = (int*)(ws + alloc((size_t)256 * 4));
    int* bounds = (int*)(ws + alloc((size_t)(NG + 1) * 4));
    float* pooledSum = (float*)(ws + alloc((size_t)NG * HID * 4));
    float* xfp       = (float*)(ws + alloc((size_t)NG * HID * 4));
    float* gbuf      = (float*)(ws + alloc((size_t)NG * HID * 4));
    (void)ws_size; (void)n_in; (void)in_sizes; (void)out_size;

    hipMemsetAsync(indeg, 0, (size_t)NN * 4, stream);
    hipMemsetAsync(pooledSum, 0, (size_t)NG * HID * 4, stream);

    // weight prep
    k_f32_to_bf16<<<(NN * CIN / 4 + 255) / 256, 256, 0, stream>>>(x_f32, xbf, NN * CIN / 4);
    k_fuse_w0<<<HID, 256, 0, stream>>>(enc_w, enc_b, conv_w0, WfT);
    k_transpose_cvt<<<dim3(16, 16), 256, 0, stream>>>(conv_w0 + HID * HID, c0T, HID, HID);
    k_transpose_cvt<<<dim3(16, 16), 256, 0, stream>>>(conv_w1, c1T, HID, HID);
    k_affine<<<1, 512, 0, stream>>>(enc_b, conv_b0, bn0_g, bn0_b, conv_b1, bn1_g, bn1_b,
                                    aff_scale, aff_shift);

    // CSR (hierarchical scan)
    k_hist<<<(NE + 255) / 256, 256, 0, stream>>>(dstp, indeg, NE);
    k_scan1<<<SCAN_NB, 256, 0, stream>>>(indeg, scan_local, scan_bsum, NN);
    k_scan2<<<1, 256, 0, stream>>>(scan_bsum, SCAN_NB);
    k_scan3<<<SCAN_NB, 256, 0, stream>>>(scan_local, scan_bsum, indeg, off, cursor, NN);
    k_fill<<<(NE + 255) / 256, 256, 0, stream>>>(srcp, dstp, cursor, csr, NE);
    k_bounds<<<1, 128, 0, stream>>>(batch, bounds);

    // layer 0 (folded): agg raw 256-dim feats (+deg col) -> K=320 GEMM -> K=512 GEMM
    k_aggregate0<<<(NN * 64) / 256, 256, 0, stream>>>(xbf, off, csr, zbuf);
    k_gemm<1, KF / 64><<<GEMM_NWG, 512, 0, stream>>>(zbuf, WfT,
                                                     aff_scale + 1 * HID, aff_shift + 1 * HID, buf0);
    k_gemm<1, HID / 64><<<GEMM_NWG, 512, 0, stream>>>(buf0, c1T,
                                                      aff_scale + 2 * HID, aff_shift + 2 * HID, buf2);

    // layer 1: agg -> GEMM (bn0[1]+relu); final GEMM folded into tail
    k_aggregate<<<(NN * 64) / 256, 256, 0, stream>>>(buf2, off, csr, buf1);
    k_gemm<1, HID / 64><<<GEMM_NWG, 512, 0, stream>>>(buf1, c0T,
                                                      aff_scale + 3 * HID, aff_shift + 3 * HID, buf2);

    // tail: pool h1, tiny fp32 GEMM + affine, then heads
    k_pool<<<dim3(NG, 8), 512, 0, stream>>>(buf2, bounds, pooledSum);
    k_tailgemm<<<NG, 512, 0, stream>>>(pooledSum, bounds, conv_w1 + HID * HID,
                                       aff_scale + 4 * HID, aff_shift + 4 * HID, xfp);
    k_head1<<<NG, 512, 0, stream>>>(xfp, lin_w, lin_b, gbuf);
    k_head2<<<NG, 128, 0, stream>>>(gbuf, clf_w, clf_b, (float*)d_out);
}

// Round 13
// 445.239 us; speedup vs baseline: 1.0887x; 1.0186x over previous
//
#include <hip/hip_runtime.h>
#include <hip/hip_bf16.h>
#include <stdint.h>

#define NN 50000
#define M_PAD 50176                         // 196 tiles of 256 rows
#define NE 400000
#define CIN 256
#define KF 320                              // fused layer-0 K: 256 feats + 1 deg col + 63 zeros
#define HID 512
#define COUT 128
#define NG 64
#define SCAN_NB ((NN + 255) / 256)          // 196
#define CVT_NB (NN * CIN / 4 / 256)         // 12500
#define HIST_NB ((NE + 255) / 256)          // 1563
#define GEMM_NWG 392                        // 196 mt x 2 nt = 392 = 8*49

typedef short bf16x8 __attribute__((ext_vector_type(8)));
typedef float f32x4 __attribute__((ext_vector_type(4)));

__device__ inline float bf2f(unsigned short u) {
    union { unsigned int i; float f; } v; v.i = ((unsigned int)u) << 16; return v.f;
}
__device__ inline unsigned short f2bf(float f) {
    union { float f; unsigned int u; } v; v.f = f;
    unsigned int r = v.u + 0x7fffu + ((v.u >> 16) & 1u);
    return (unsigned short)(r >> 16);
}

__device__ inline void async16(const void* g, void* l) {
    __builtin_amdgcn_global_load_lds((const __attribute__((address_space(1))) void*)g,
                                     (__attribute__((address_space(3))) void*)l, 16, 0, 0);
}

// ---------------- merged prep: f32->bf16 cvt + indegree histogram ----------------

__global__ void k_prep0(const float* __restrict__ xf, unsigned short* __restrict__ xbf,
                        const int* __restrict__ dst, int* __restrict__ indeg) {
    int b = blockIdx.x;
    if (b < CVT_NB) {
        int i = b * 256 + threadIdx.x;
        float4 v = ((const float4*)xf)[i];
        ushort4 o;
        o.x = f2bf(v.x); o.y = f2bf(v.y); o.z = f2bf(v.z); o.w = f2bf(v.w);
        ((ushort4*)xbf)[i] = o;
    } else {
        int i = (b - CVT_NB) * 256 + threadIdx.x;
        if (i < NE) atomicAdd(&indeg[dst[i]], 1);
    }
}

// two 512x512 f32->bf16 transposes in one launch (z selects pair)
__global__ void k_transpose2(const float* __restrict__ s0, const float* __restrict__ s1,
                             unsigned short* __restrict__ d0, unsigned short* __restrict__ d1) {
    const float* in = blockIdx.z ? s1 : s0;
    unsigned short* out = blockIdx.z ? d1 : d0;
    __shared__ float tile[32][33];
    int bx = blockIdx.x * 32, by = blockIdx.y * 32;
    int tx = threadIdx.x & 31, ty = threadIdx.x >> 5;
    for (int i = 0; i < 32; i += 8)
        tile[ty + i][tx] = in[(size_t)(by + ty + i) * HID + bx + tx];
    __syncthreads();
    for (int i = 0; i < 32; i += 8)
        out[(size_t)(bx + ty + i) * HID + by + tx] = f2bf(tile[tx][ty + i]);
}

// fused layer-0 weight: WfT[n][k] = (enc_w @ W0)[k][n] for k<256; row 256 = enc_b@W0; rest 0
__global__ void k_fuse_w0(const float* __restrict__ enc_w, const float* __restrict__ enc_b,
                          const float* __restrict__ W0, unsigned short* __restrict__ WfT) {
    int n = blockIdx.x;                 // 0..511
    __shared__ float col[HID];
    for (int j = threadIdx.x; j < HID; j += 256) col[j] = W0[(size_t)j * HID + n];
    __syncthreads();
    int k = threadIdx.x;                // 0..255
    float acc = 0.f;
    for (int j = 0; j < HID; j++) acc += enc_w[(size_t)k * HID + j] * col[j];
    WfT[(size_t)n * KF + k] = f2bf(acc);
    if (k == 0) {
        float v = 0.f;
        for (int j = 0; j < HID; j++) v += enc_b[j] * col[j];
        WfT[(size_t)n * KF + 256] = f2bf(v);
    }
    if (k >= 1 && k < 64) WfT[(size_t)n * KF + 256 + k] = 0;
}

// merged: per-column scale/shift (indices 1..4 used) + graph bounds binary search
__global__ void k_affine_bounds(const float* __restrict__ enc_b,
                                const float* __restrict__ cb0, const float* __restrict__ bg0, const float* __restrict__ bb0,
                                const float* __restrict__ cb1, const float* __restrict__ bg1, const float* __restrict__ bb1,
                                float* __restrict__ scale, float* __restrict__ shift,
                                const int* __restrict__ batch, int* __restrict__ bounds) {
    int c = threadIdx.x; // 512
    const float inv = 0.9999950000374997f; // 1/sqrt(1+1e-5)
    scale[c] = 1.f; shift[c] = enc_b[c];
    for (int l = 0; l < 2; l++) {
        float s0 = bg0[l * HID + c] * inv;
        scale[(1 + 2 * l) * HID + c] = s0;
        shift[(1 + 2 * l) * HID + c] = cb0[l * HID + c] * s0 + bb0[l * HID + c];
        float s1 = bg1[l * HID + c] * inv;
        scale[(2 + 2 * l) * HID + c] = s1;
        shift[(2 + 2 * l) * HID + c] = cb1[l * HID + c] * s1 + bb1[l * HID + c];
    }
    if (c <= NG) {
        int lo = 0, hi = NN;
        while (lo < hi) { int mid = (lo + hi) >> 1; if (batch[mid] < c) lo = mid + 1; else hi = mid; }
        bounds[c] = lo;
    }
}

// ---------------- CSR scan (2 kernels: block-local scan, then offset apply) ----------------

__global__ void k_scan1(const int* __restrict__ indeg, int* __restrict__ local,
                        int* __restrict__ blocksum, int n) {
    __shared__ int s[256];
    int t = threadIdx.x;
    int i = blockIdx.x * 256 + t;
    int v = (i < n) ? indeg[i] : 0;
    s[t] = v;
    __syncthreads();
    for (int d = 1; d < 256; d <<= 1) {
        int u = (t >= d) ? s[t - d] : 0;
        __syncthreads();
        s[t] += u;
        __syncthreads();
    }
    if (i < n) local[i] = s[t] - v;
    if (t == 255) blocksum[blockIdx.x] = s[255];
}

// each block computes its own exclusive prefix of blocksum via parallel LDS reduce
__global__ void k_scan3(const int* __restrict__ local, const int* __restrict__ blocksum,
                        const int* __restrict__ indeg, int* __restrict__ off,
                        int* __restrict__ cursor, int n) {
    __shared__ int s[256];
    int t = threadIdx.x;
    s[t] = (t < blockIdx.x && t < SCAN_NB) ? blocksum[t] : 0;
    __syncthreads();
    for (int d = 128; d > 0; d >>= 1) {
        if (t < d) s[t] += s[t + d];
        __syncthreads();
    }
    int ps = s[0];
    int i = blockIdx.x * 256 + t;
    if (i < n) {
        int o = local[i] + ps;
        off[i] = o;
        cursor[i] = o;
        if (i == n - 1) off[n] = o + indeg[i];
    }
}

__global__ void k_fill(const int* __restrict__ src, const int* __restrict__ dst,
                       int* __restrict__ cursor, int* __restrict__ csr, int n) {
    int i = blockIdx.x * blockDim.x + threadIdx.x;
    if (i < n) {
        int p = atomicAdd(&cursor[dst[i]], 1);
        csr[p] = src[i];
    }
}

// ---------------- layer-0 aggregation on RAW 256-dim features + deg column ----------------

__global__ void k_aggregate0(const unsigned short* __restrict__ x, const int* __restrict__ off,
                             const int* __restrict__ csr, unsigned short* __restrict__ z) {
    int wid = (int)((blockIdx.x * blockDim.x + threadIdx.x) >> 6);
    if (wid >= NN) return;
    int lane = threadIdx.x & 63;
    const uint2* xr = (const uint2*)x; // row = 64 uint2 (256 bf16)
    uint2 v = xr[(size_t)wid * 64 + lane];
    float acc[4];
    {
        unsigned short* p = (unsigned short*)&v;
        for (int i = 0; i < 4; i++) acc[i] = bf2f(p[i]);
    }
    int e0 = off[wid], e1 = off[wid + 1];
    int e = e0;
    for (; e + 7 < e1; e += 8) {
        uint2 vv[8];
#pragma unroll
        for (int q = 0; q < 8; q++) vv[q] = xr[(size_t)csr[e + q] * 64 + lane];
#pragma unroll
        for (int q = 0; q < 8; q++) {
            unsigned short* p = (unsigned short*)&vv[q];
#pragma unroll
            for (int i = 0; i < 4; i++) acc[i] += bf2f(p[i]);
        }
    }
    for (; e < e1; e++) {
        int u = csr[e];
        uint2 vu = xr[(size_t)u * 64 + lane];
        unsigned short* p = (unsigned short*)&vu;
#pragma unroll
        for (int i = 0; i < 4; i++) acc[i] += bf2f(p[i]);
    }
    uint2 o;
    unsigned short* po = (unsigned short*)&o;
    for (int i = 0; i < 4; i++) po[i] = f2bf(acc[i]);
    uint2* zr = (uint2*)z; // row = 80 uint2 (320 bf16)
    zr[(size_t)wid * 80 + lane] = o;
    if (lane < 16) {
        uint2 ex; ex.x = 0; ex.y = 0;
        if (lane == 0) ex.x = (unsigned)f2bf((float)(1 + e1 - e0));
        zr[(size_t)wid * 80 + 64 + lane] = ex;
    }
}

// ---------------- layer-1 aggregation: 512-dim ----------------

__global__ void k_aggregate(const unsigned short* __restrict__ x, const int* __restrict__ off,
                            const int* __restrict__ csr, unsigned short* __restrict__ h) {
    int wid = (int)((blockIdx.x * blockDim.x + threadIdx.x) >> 6);
    if (wid >= NN) return;
    int lane = threadIdx.x & 63;
    const uint4* xr = (const uint4*)x;
    uint4 v = xr[(size_t)wid * 64 + lane];
    float acc[8];
    {
        unsigned short* p = (unsigned short*)&v;
        for (int i = 0; i < 8; i++) acc[i] = bf2f(p[i]);
    }
    int e0 = off[wid], e1 = off[wid + 1];
    int e = e0;
    for (; e + 7 < e1; e += 8) {
        uint4 vv[8];
#pragma unroll
        for (int q = 0; q < 8; q++) vv[q] = xr[(size_t)csr[e + q] * 64 + lane];
#pragma unroll
        for (int q = 0; q < 8; q++) {
            unsigned short* p = (unsigned short*)&vv[q];
#pragma unroll
            for (int i = 0; i < 8; i++) acc[i] += bf2f(p[i]);
        }
    }
    for (; e < e1; e++) {
        int u = csr[e];
        uint4 vu = xr[(size_t)u * 64 + lane];
        unsigned short* p = (unsigned short*)&vu;
#pragma unroll
        for (int i = 0; i < 8; i++) acc[i] += bf2f(p[i]);
    }
    uint4 o;
    unsigned short* po = (unsigned short*)&o;
    for (int i = 0; i < 8; i++) po[i] = f2bf(acc[i]);
    ((uint4*)h)[(size_t)wid * 64 + lane] = o;
}

// ---------------- bf16 MFMA GEMM: BM=256 x BN=256, 8 waves, counted-vmcnt (R12-verified) ----

template <int RELU, int NSTEPS>
__global__ __launch_bounds__(512, 2) void k_gemm(const unsigned short* __restrict__ A,
                                                 const unsigned short* __restrict__ WT,
                                                 const float* __restrict__ scale,
                                                 const float* __restrict__ shift,
                                                 unsigned short* __restrict__ out) {
    constexpr int K = NSTEPS * 64;
    __shared__ char lds[131072];
    const int tid = threadIdx.x, w = tid >> 6, lane = tid & 63;
    const int wr = w >> 2, wc = w & 3;
    const int lr = lane & 15, lh = lane >> 4;

    int orig = blockIdx.x;
    int wgid = (orig & 7) * 49 + (orig >> 3);
    int tile_m = (wgid >> 1) * 256;
    int n0 = (wgid & 1) * 256;

    const unsigned short* gA[4];
    const unsigned short* gB[4];
    int ldsoff[4];
#pragma unroll
    for (int ci = 0; ci < 4; ci++) {
        int c = w * 4 + ci;
        int f = c >> 1, kf = c & 1;
        ldsoff[ci] = c * 1024;
        gA[ci] = A + (size_t)(tile_m + f * 16 + lr) * K + kf * 32 + lh * 8;
        gB[ci] = WT + (size_t)(n0 + f * 16 + lr) * K + kf * 32 + lh * 8;
    }

    f32x4 acc[8][4];
#pragma unroll
    for (int x = 0; x < 8; x++)
#pragma unroll
        for (int y = 0; y < 4; y++) acc[x][y] = f32x4{0.f, 0.f, 0.f, 0.f};

#pragma unroll
    for (int ci = 0; ci < 4; ci++) async16(gA[ci], lds + ldsoff[ci]);
#pragma unroll
    for (int ci = 0; ci < 4; ci++) async16(gB[ci], lds + 32768 + ldsoff[ci]);
#pragma unroll
    for (int ci = 0; ci < 4; ci++) async16(gA[ci] + 64, lds + 65536 + ldsoff[ci]);
#pragma unroll
    for (int ci = 0; ci < 4; ci++) async16(gB[ci] + 64, lds + 65536 + 32768 + ldsoff[ci]);

#pragma unroll
    for (int ks = 0; ks < NSTEPS; ks++) {
        const int cur = (ks & 1) << 16;
        if (ks < NSTEPS - 1) asm volatile("s_waitcnt vmcnt(8)" ::: "memory");
        else                 asm volatile("s_waitcnt vmcnt(0)" ::: "memory");
        __builtin_amdgcn_s_barrier();
        __builtin_amdgcn_sched_barrier(0);
#pragma unroll
        for (int kf = 0; kf < 2; kf++) {
            bf16x8 a[8], bb[4];
#pragma unroll
            for (int mf = 0; mf < 8; mf++)
                a[mf] = *(const bf16x8*)(lds + cur + ((wr * 8 + mf) * 2 + kf) * 1024 + lane * 16);
#pragma unroll
            for (int nf = 0; nf < 4; nf++)
                bb[nf] = *(const bf16x8*)(lds + cur + 32768 + ((wc * 4 + nf) * 2 + kf) * 1024 + lane * 16);
#pragma unroll
            for (int mf = 0; mf < 8; mf++)
#pragma unroll
                for (int nf = 0; nf < 4; nf++)
                    acc[mf][nf] = __builtin_amdgcn_mfma_f32_16x16x32_bf16(bb[nf], a[mf], acc[mf][nf], 0, 0, 0);
        }
        __builtin_amdgcn_sched_barrier(0);
        __builtin_amdgcn_s_barrier();
        if (ks + 2 < NSTEPS) {
            int ko = (ks + 2) << 6;
#pragma unroll
            for (int ci = 0; ci < 4; ci++) async16(gA[ci] + ko, lds + cur + ldsoff[ci]);
#pragma unroll
            for (int ci = 0; ci < 4; ci++) async16(gB[ci] + ko, lds + cur + 32768 + ldsoff[ci]);
        }
    }

#pragma unroll
    for (int nf = 0; nf < 4; nf++) {
        int col = n0 + wc * 64 + nf * 16 + lh * 4;
        float4 sc = *(const float4*)&scale[col];
        float4 sh = *(const float4*)&shift[col];
#pragma unroll
        for (int mf = 0; mf < 8; mf++) {
            int row = tile_m + wr * 128 + mf * 16 + lr;
            float y0 = acc[mf][nf][0] * sc.x + sh.x;
            float y1 = acc[mf][nf][1] * sc.y + sh.y;
            float y2 = acc[mf][nf][2] * sc.z + sh.z;
            float y3 = acc[mf][nf][3] * sc.w + sh.w;
            if (RELU) {
                y0 = fmaxf(y0, 0.f); y1 = fmaxf(y1, 0.f);
                y2 = fmaxf(y2, 0.f); y3 = fmaxf(y3, 0.f);
            }
            ushort4 pk;
            pk.x = f2bf(y0); pk.y = f2bf(y1); pk.z = f2bf(y2); pk.w = f2bf(y3);
            *(ushort4*)(out + (size_t)row * HID + col) = pk;
        }
    }
}

// ---------------- pooling + merged tail ----------------

__global__ void k_pool(const unsigned short* __restrict__ x, const int* __restrict__ bounds,
                       float* __restrict__ pooled) {
    int g = blockIdx.x, s = blockIdx.y, t = threadIdx.x; // 512 thr
    int b0 = bounds[g], b1 = bounds[g + 1];
    int len = b1 - b0;
    int r0 = b0 + (int)((long long)len * s / 8);
    int r1 = b0 + (int)((long long)len * (s + 1) / 8);
    float acc = 0.f;
    for (int r = r0; r < r1; r++) acc += bf2f(x[(size_t)r * HID + t]);
    if (r1 > r0) atomicAdd(&pooled[g * HID + t], acc);
}

// merged tail: mean -> @W1*s+sh -> @lin_w+lin_b -> gelu -> @clf_w+clf_b
__global__ void k_tail(const float* __restrict__ pooledSum, const int* __restrict__ bounds,
                       const float* __restrict__ W1, const float* __restrict__ scale,
                       const float* __restrict__ shift,
                       const float* __restrict__ lin_w, const float* __restrict__ lin_b,
                       const float* __restrict__ clf_w, const float* __restrict__ clf_b,
                       float* __restrict__ out) {
    int g = blockIdx.x, t = threadIdx.x; // 64 blocks x 512 thr
    __shared__ float r0[HID], r1[HID], r2[HID];
    int cnt = bounds[g + 1] - bounds[g];
    float invc = 1.f / fmaxf((float)cnt, 1.f);
    r0[t] = pooledSum[g * HID + t] * invc;
    __syncthreads();
    {
        float acc = 0.f;
        for (int k = 0; k < HID; k++) acc += r0[k] * W1[(size_t)k * HID + t];
        r1[t] = acc * scale[t] + shift[t];
    }
    __syncthreads();
    {
        float acc = lin_b[t];
        for (int k = 0; k < HID; k++) acc += r1[k] * lin_w[(size_t)k * HID + t];
        r2[t] = 0.5f * acc * (1.f + erff(acc * 0.7071067811865475f));
    }
    __syncthreads();
    if (t < COUT) {
        float acc = clf_b[t];
        for (int k = 0; k < HID; k++) acc += r2[k] * clf_w[(size_t)k * COUT + t];
        out[g * COUT + t] = acc;
    }
}

// ---------------- launch ----------------

extern "C" void kernel_launch(void* const* d_in, const int* in_sizes, int n_in,
                              void* d_out, int out_size, void* d_ws, size_t ws_size,
                              hipStream_t stream) {
    const float* x_f32   = (const float*)d_in[0];
    const int*   ei      = (const int*)d_in[1];
    const int*   batch   = (const int*)d_in[2];
    const float* enc_w   = (const float*)d_in[3];
    const float* enc_b   = (const float*)d_in[4];
    const float* conv_w0 = (const float*)d_in[5];
    const float* conv_b0 = (const float*)d_in[6];
    const float* bn0_g   = (const float*)d_in[7];
    const float* bn0_b   = (const float*)d_in[8];
    const float* conv_w1 = (const float*)d_in[9];
    const float* conv_b1 = (const float*)d_in[10];
    const float* bn1_g   = (const float*)d_in[11];
    const float* bn1_b   = (const float*)d_in[12];
    const float* lin_w   = (const float*)d_in[13];
    const float* lin_b   = (const float*)d_in[14];
    const float* clf_w   = (const float*)d_in[15];
    const float* clf_b   = (const float*)d_in[16];
    const int* srcp = ei;
    const int* dstp = ei + NE;

    char* ws = (char*)d_ws;
    size_t o = 0;
    auto alloc = [&](size_t b) { size_t r = o; o += (b + 255) & ~(size_t)255; return r; };
    unsigned short* buf0 = (unsigned short*)(ws + alloc((size_t)M_PAD * HID * 2));
    unsigned short* buf1 = (unsigned short*)(ws + alloc((size_t)M_PAD * HID * 2));
    unsigned short* buf2 = (unsigned short*)(ws + alloc((size_t)M_PAD * HID * 2));
    unsigned short* xbf  = buf0;  // alias: raw bf16 feats [NN][256]; dead after k_aggregate0
    unsigned short* zbuf = buf2;  // alias: agg0 output [M_PAD][320]; dead after l0 GEMM
    unsigned short* WfT  = (unsigned short*)(ws + alloc((size_t)HID * KF * 2));
    unsigned short* c0T  = (unsigned short*)(ws + alloc((size_t)HID * HID * 2)); // conv_w0[1]^T
    unsigned short* c1T  = (unsigned short*)(ws + alloc((size_t)HID * HID * 2)); // conv_w1[0]^T
    float* aff_scale = (float*)(ws + alloc(5 * HID * 4));
    float* aff_shift = (float*)(ws + alloc(5 * HID * 4));
    int* indeg  = (int*)(ws + alloc((size_t)NN * 4));
    int* off    = (int*)(ws + alloc((size_t)(NN + 1) * 4));
    int* cursor = (int*)(ws + alloc((size_t)NN * 4));
    int* csr    = (int*)(ws + alloc((size_t)NE * 4));
    int* scan_local = (int*)(ws + alloc((size_t)NN * 4));
    int* scan_bsum  = (int*)(ws + alloc((size_t)256 * 4));
    int* bounds = (int*)(ws + alloc((size_t)(NG + 1) * 4));
    float* pooledSum = (float*)(ws + alloc((size_t)NG * HID * 4));
    (void)ws_size; (void)n_in; (void)in_sizes; (void)out_size;

    hipMemsetAsync(indeg, 0, (size_t)NN * 4, stream);
    hipMemsetAsync(pooledSum, 0, (size_t)NG * HID * 4, stream);

    // prep (merged): cvt + hist | fused W | transposes | affine+bounds
    k_prep0<<<CVT_NB + HIST_NB, 256, 0, stream>>>(x_f32, xbf, dstp, indeg);
    k_fuse_w0<<<HID, 256, 0, stream>>>(enc_w, enc_b, conv_w0, WfT);
    k_transpose2<<<dim3(16, 16, 2), 256, 0, stream>>>(conv_w0 + HID * HID, conv_w1, c0T, c1T);
    k_affine_bounds<<<1, 512, 0, stream>>>(enc_b, conv_b0, bn0_g, bn0_b, conv_b1, bn1_g, bn1_b,
                                           aff_scale, aff_shift, batch, bounds);

    // CSR (2-kernel scan)
    k_scan1<<<SCAN_NB, 256, 0, stream>>>(indeg, scan_local, scan_bsum, NN);
    k_scan3<<<SCAN_NB, 256, 0, stream>>>(scan_local, scan_bsum, indeg, off, cursor, NN);
    k_fill<<<HIST_NB, 256, 0, stream>>>(srcp, dstp, cursor, csr, NE);

    // layer 0 (folded): agg raw 256-dim feats (+deg col) -> K=320 GEMM -> K=512 GEMM
    k_aggregate0<<<(NN * 64) / 256, 256, 0, stream>>>(xbf, off, csr, zbuf);
    k_gemm<1, KF / 64><<<GEMM_NWG, 512, 0, stream>>>(zbuf, WfT,
                                                     aff_scale + 1 * HID, aff_shift + 1 * HID, buf0);
    k_gemm<1, HID / 64><<<GEMM_NWG, 512, 0, stream>>>(buf0, c1T,
                                                      aff_scale + 2 * HID, aff_shift + 2 * HID, buf2);

    // layer 1: agg -> GEMM (bn0[1]+relu); final GEMM folded into tail
    k_aggregate<<<(NN * 64) / 256, 256, 0, stream>>>(buf2, off, csr, buf1);
    k_gemm<1, HID / 64><<<GEMM_NWG, 512, 0, stream>>>(buf1, c0T,
                                                      aff_scale + 3 * HID, aff_shift + 3 * HID, buf2);

    // tail: pool h1, then one merged kernel (mean -> W1+bn -> lin+gelu -> clf)
    k_pool<<<dim3(NG, 8), 512, 0, stream>>>(buf2, bounds, pooledSum);
    k_tail<<<NG, 512, 0, stream>>>(pooledSum, bounds, conv_w1 + HID * HID,
                                   aff_scale + 4 * HID, aff_shift + 4 * HID,
                                   lin_w, lin_b, clf_w, clf_b, (float*)d_out);
}

// Round 14
// 443.743 us; speedup vs baseline: 1.0924x; 1.0034x over previous
//
#include <hip/hip_runtime.h>
#include <hip/hip_bf16.h>
#include <stdint.h>

#define NN 50000
#define M_PAD 50176                         // 196 tiles of 256 rows
#define NE 400000
#define CIN 256
#define KF 320                              // fused layer-0 K: 256 feats + 1 deg col + 63 zeros
#define HID 512
#define COUT 128
#define NG 64
#define SCAN_NB ((NN + 255) / 256)          // 196
#define CVT_NB (NN * CIN / 4 / 256)         // 12500
#define HIST_NB ((NE + 255) / 256)          // 1563
#define GEMM_NWG 392                        // 196 mt x 2 nt = 392 = 8*49

typedef short bf16x8 __attribute__((ext_vector_type(8)));
typedef float f32x4 __attribute__((ext_vector_type(4)));

__device__ inline float bf2f(unsigned short u) {
    union { unsigned int i; float f; } v; v.i = ((unsigned int)u) << 16; return v.f;
}
__device__ inline unsigned short f2bf(float f) {
    union { float f; unsigned int u; } v; v.f = f;
    unsigned int r = v.u + 0x7fffu + ((v.u >> 16) & 1u);
    return (unsigned short)(r >> 16);
}

__device__ inline void async16(const void* g, void* l) {
    __builtin_amdgcn_global_load_lds((const __attribute__((address_space(1))) void*)g,
                                     (__attribute__((address_space(3))) void*)l, 16, 0, 0);
}

// ---------------- merged prep: f32->bf16 cvt + indegree histogram ----------------

__global__ void k_prep0(const float* __restrict__ xf, unsigned short* __restrict__ xbf,
                        const int* __restrict__ dst, int* __restrict__ indeg) {
    int b = blockIdx.x;
    if (b < CVT_NB) {
        int i = b * 256 + threadIdx.x;
        float4 v = ((const float4*)xf)[i];
        ushort4 o;
        o.x = f2bf(v.x); o.y = f2bf(v.y); o.z = f2bf(v.z); o.w = f2bf(v.w);
        ((ushort4*)xbf)[i] = o;
    } else {
        int i = (b - CVT_NB) * 256 + threadIdx.x;
        if (i < NE) atomicAdd(&indeg[dst[i]], 1);
    }
}

// two 512x512 f32->bf16 transposes in one launch (z selects pair)
__global__ void k_transpose2(const float* __restrict__ s0, const float* __restrict__ s1,
                             unsigned short* __restrict__ d0, unsigned short* __restrict__ d1) {
    const float* in = blockIdx.z ? s1 : s0;
    unsigned short* out = blockIdx.z ? d1 : d0;
    __shared__ float tile[32][33];
    int bx = blockIdx.x * 32, by = blockIdx.y * 32;
    int tx = threadIdx.x & 31, ty = threadIdx.x >> 5;
    for (int i = 0; i < 32; i += 8)
        tile[ty + i][tx] = in[(size_t)(by + ty + i) * HID + bx + tx];
    __syncthreads();
    for (int i = 0; i < 32; i += 8)
        out[(size_t)(bx + ty + i) * HID + by + tx] = f2bf(tile[tx][ty + i]);
}

// fused layer-0 weight: WfT[n][k] = (enc_w @ W0)[k][n] for k<256; row 256 = enc_b@W0; rest 0
__global__ void k_fuse_w0(const float* __restrict__ enc_w, const float* __restrict__ enc_b,
                          const float* __restrict__ W0, unsigned short* __restrict__ WfT) {
    int n = blockIdx.x;                 // 0..511
    __shared__ float col[HID];
    for (int j = threadIdx.x; j < HID; j += 256) col[j] = W0[(size_t)j * HID + n];
    __syncthreads();
    int k = threadIdx.x;                // 0..255
    float acc = 0.f;
    for (int j = 0; j < HID; j++) acc += enc_w[(size_t)k * HID + j] * col[j];
    WfT[(size_t)n * KF + k] = f2bf(acc);
    if (k == 0) {
        float v = 0.f;
        for (int j = 0; j < HID; j++) v += enc_b[j] * col[j];
        WfT[(size_t)n * KF + 256] = f2bf(v);
    }
    if (k >= 1 && k < 64) WfT[(size_t)n * KF + 256 + k] = 0;
}

// merged: per-column scale/shift (indices 1..4 used) + graph bounds binary search
__global__ void k_affine_bounds(const float* __restrict__ enc_b,
                                const float* __restrict__ cb0, const float* __restrict__ bg0, const float* __restrict__ bb0,
                                const float* __restrict__ cb1, const float* __restrict__ bg1, const float* __restrict__ bb1,
                                float* __restrict__ scale, float* __restrict__ shift,
                                const int* __restrict__ batch, int* __restrict__ bounds) {
    int c = threadIdx.x; // 512
    const float inv = 0.9999950000374997f; // 1/sqrt(1+1e-5)
    scale[c] = 1.f; shift[c] = enc_b[c];
    for (int l = 0; l < 2; l++) {
        float s0 = bg0[l * HID + c] * inv;
        scale[(1 + 2 * l) * HID + c] = s0;
        shift[(1 + 2 * l) * HID + c] = cb0[l * HID + c] * s0 + bb0[l * HID + c];
        float s1 = bg1[l * HID + c] * inv;
        scale[(2 + 2 * l) * HID + c] = s1;
        shift[(2 + 2 * l) * HID + c] = cb1[l * HID + c] * s1 + bb1[l * HID + c];
    }
    if (c <= NG) {
        int lo = 0, hi = NN;
        while (lo < hi) { int mid = (lo + hi) >> 1; if (batch[mid] < c) lo = mid + 1; else hi = mid; }
        bounds[c] = lo;
    }
}

// ---------------- CSR scan (2 kernels: block-local scan, then offset apply) ----------------

__global__ void k_scan1(const int* __restrict__ indeg, int* __restrict__ local,
                        int* __restrict__ blocksum, int n) {
    __shared__ int s[256];
    int t = threadIdx.x;
    int i = blockIdx.x * 256 + t;
    int v = (i < n) ? indeg[i] : 0;
    s[t] = v;
    __syncthreads();
    for (int d = 1; d < 256; d <<= 1) {
        int u = (t >= d) ? s[t - d] : 0;
        __syncthreads();
        s[t] += u;
        __syncthreads();
    }
    if (i < n) local[i] = s[t] - v;
    if (t == 255) blocksum[blockIdx.x] = s[255];
}

__global__ void k_scan3(const int* __restrict__ local, const int* __restrict__ blocksum,
                        const int* __restrict__ indeg, int* __restrict__ off,
                        int* __restrict__ cursor, int n) {
    __shared__ int s[256];
    int t = threadIdx.x;
    s[t] = (t < blockIdx.x && t < SCAN_NB) ? blocksum[t] : 0;
    __syncthreads();
    for (int d = 128; d > 0; d >>= 1) {
        if (t < d) s[t] += s[t + d];
        __syncthreads();
    }
    int ps = s[0];
    int i = blockIdx.x * 256 + t;
    if (i < n) {
        int o = local[i] + ps;
        off[i] = o;
        cursor[i] = o;
        if (i == n - 1) off[n] = o + indeg[i];
    }
}

__global__ void k_fill(const int* __restrict__ src, const int* __restrict__ dst,
                       int* __restrict__ cursor, int* __restrict__ csr, int n) {
    int i = blockIdx.x * blockDim.x + threadIdx.x;
    if (i < n) {
        int p = atomicAdd(&cursor[dst[i]], 1);
        csr[p] = src[i];
    }
}

// ---------------- layer-0 aggregation on RAW 256-dim features + deg column ----------------

__global__ void k_aggregate0(const unsigned short* __restrict__ x, const int* __restrict__ off,
                             const int* __restrict__ csr, unsigned short* __restrict__ z) {
    int wid = (int)((blockIdx.x * blockDim.x + threadIdx.x) >> 6);
    if (wid >= NN) return;
    int lane = threadIdx.x & 63;
    const uint2* xr = (const uint2*)x; // row = 64 uint2 (256 bf16)
    uint2 v = xr[(size_t)wid * 64 + lane];
    float acc[4];
    {
        unsigned short* p = (unsigned short*)&v;
        for (int i = 0; i < 4; i++) acc[i] = bf2f(p[i]);
    }
    int e0 = off[wid], e1 = off[wid + 1];
    int e = e0;
    for (; e + 7 < e1; e += 8) {
        uint2 vv[8];
#pragma unroll
        for (int q = 0; q < 8; q++) vv[q] = xr[(size_t)csr[e + q] * 64 + lane];
#pragma unroll
        for (int q = 0; q < 8; q++) {
            unsigned short* p = (unsigned short*)&vv[q];
#pragma unroll
            for (int i = 0; i < 4; i++) acc[i] += bf2f(p[i]);
        }
    }
    for (; e < e1; e++) {
        int u = csr[e];
        uint2 vu = xr[(size_t)u * 64 + lane];
        unsigned short* p = (unsigned short*)&vu;
#pragma unroll
        for (int i = 0; i < 4; i++) acc[i] += bf2f(p[i]);
    }
    uint2 o;
    unsigned short* po = (unsigned short*)&o;
    for (int i = 0; i < 4; i++) po[i] = f2bf(acc[i]);
    uint2* zr = (uint2*)z; // row = 80 uint2 (320 bf16)
    zr[(size_t)wid * 80 + lane] = o;
    if (lane < 16) {
        uint2 ex; ex.x = 0; ex.y = 0;
        if (lane == 0) ex.x = (unsigned)f2bf((float)(1 + e1 - e0));
        zr[(size_t)wid * 80 + 64 + lane] = ex;
    }
}

// ---------------- layer-1 aggregation: 512-dim ----------------

__global__ void k_aggregate(const unsigned short* __restrict__ x, const int* __restrict__ off,
                            const int* __restrict__ csr, unsigned short* __restrict__ h) {
    int wid = (int)((blockIdx.x * blockDim.x + threadIdx.x) >> 6);
    if (wid >= NN) return;
    int lane = threadIdx.x & 63;
    const uint4* xr = (const uint4*)x;
    uint4 v = xr[(size_t)wid * 64 + lane];
    float acc[8];
    {
        unsigned short* p = (unsigned short*)&v;
        for (int i = 0; i < 8; i++) acc[i] = bf2f(p[i]);
    }
    int e0 = off[wid], e1 = off[wid + 1];
    int e = e0;
    for (; e + 7 < e1; e += 8) {
        uint4 vv[8];
#pragma unroll
        for (int q = 0; q < 8; q++) vv[q] = xr[(size_t)csr[e + q] * 64 + lane];
#pragma unroll
        for (int q = 0; q < 8; q++) {
            unsigned short* p = (unsigned short*)&vv[q];
#pragma unroll
            for (int i = 0; i < 8; i++) acc[i] += bf2f(p[i]);
        }
    }
    for (; e < e1; e++) {
        int u = csr[e];
        uint4 vu = xr[(size_t)u * 64 + lane];
        unsigned short* p = (unsigned short*)&vu;
#pragma unroll
        for (int i = 0; i < 8; i++) acc[i] += bf2f(p[i]);
    }
    uint4 o;
    unsigned short* po = (unsigned short*)&o;
    for (int i = 0; i < 8; i++) po[i] = f2bf(acc[i]);
    ((uint4*)h)[(size_t)wid * 64 + lane] = o;
}

// ---------------- bf16 MFMA GEMM: BM=256 x BN=256, 8 waves, 4-QUADRANT-PHASE schedule ----
// T3+T4+T5 port of the 8-phase template onto the R12 skeleton. Per K-tile t:
// 4 Gray-order quadrant phases (mh0nh0 -> mh0nh1 -> mh1nh1 -> mh1nh0); A/B register
// halves persist across phases (24 ds_read_b128/tile, unchanged); 2 staging issues per
// phase (8/tile into nxt); ONE vmcnt per tile: queue = [tile's 8][2 just issued] ->
// vmcnt(2) uniform (prologue + steady), vmcnt(0) last tile only. Barriers pace phases;
// setprio(1) around each 16-MFMA cluster (role diversity from phase split -> T5 pays).
// Race-free: stages target nxt whose readers all crossed the prior tile's last barrier.
// MFMA order per accumulator unchanged -> bit-identical output vs R12.

template <int RELU, int NSTEPS>
__global__ __launch_bounds__(512, 2) void k_gemm(const unsigned short* __restrict__ A,
                                                 const unsigned short* __restrict__ WT,
                                                 const float* __restrict__ scale,
                                                 const float* __restrict__ shift,
                                                 unsigned short* __restrict__ out) {
    constexpr int K = NSTEPS * 64;
    __shared__ char lds[131072];
    const int tid = threadIdx.x, w = tid >> 6, lane = tid & 63;
    const int wr = w >> 2, wc = w & 3;
    const int lr = lane & 15, lh = lane >> 4;

    int orig = blockIdx.x;
    int wgid = (orig & 7) * 49 + (orig >> 3);
    int tile_m = (wgid >> 1) * 256;
    int n0 = (wgid & 1) * 256;

    const unsigned short* gA[4];
    const unsigned short* gB[4];
    int ldsoff[4];
#pragma unroll
    for (int ci = 0; ci < 4; ci++) {
        int c = w * 4 + ci;
        int f = c >> 1, kf = c & 1;
        ldsoff[ci] = c * 1024;
        gA[ci] = A + (size_t)(tile_m + f * 16 + lr) * K + kf * 32 + lh * 8;
        gB[ci] = WT + (size_t)(n0 + f * 16 + lr) * K + kf * 32 + lh * 8;
    }

    f32x4 acc[8][4];
#pragma unroll
    for (int x = 0; x < 8; x++)
#pragma unroll
        for (int y = 0; y < 4; y++) acc[x][y] = f32x4{0.f, 0.f, 0.f, 0.f};

    // prologue: tile 0's A+B into buf0 (8 loads/thread in flight)
#pragma unroll
    for (int ci = 0; ci < 4; ci++) async16(gA[ci], lds + ldsoff[ci]);
#pragma unroll
    for (int ci = 0; ci < 4; ci++) async16(gB[ci], lds + 32768 + ldsoff[ci]);

#pragma unroll
    for (int t = 0; t < NSTEPS; t++) {
        const int cur = (t & 1) << 16;
        const int nxt = cur ^ 65536;
        const int ko = (t + 1) << 6;
        const bool pf = (t + 1 < NSTEPS);

        bf16x8 aLo[8], aHi[8], bLo[4], bHi[4];

        // ---- phase 0: quad (mh0, nh0) ----
        if (pf) {
            async16(gA[0] + ko, lds + nxt + ldsoff[0]);
            async16(gA[1] + ko, lds + nxt + ldsoff[1]);
            asm volatile("s_waitcnt vmcnt(2)" ::: "memory");
        } else {
            asm volatile("s_waitcnt vmcnt(0)" ::: "memory");
        }
        __builtin_amdgcn_s_barrier();               // cur valid for all waves
        __builtin_amdgcn_sched_barrier(0);
#pragma unroll
        for (int mf = 0; mf < 4; mf++)
#pragma unroll
            for (int kf = 0; kf < 2; kf++)
                aLo[mf * 2 + kf] = *(const bf16x8*)(lds + cur + ((wr * 8 + mf) * 2 + kf) * 1024 + lane * 16);
#pragma unroll
        for (int nf = 0; nf < 2; nf++)
#pragma unroll
            for (int kf = 0; kf < 2; kf++)
                bLo[nf * 2 + kf] = *(const bf16x8*)(lds + cur + 32768 + ((wc * 4 + nf) * 2 + kf) * 1024 + lane * 16);
        __builtin_amdgcn_s_setprio(1);
#pragma unroll
        for (int kf = 0; kf < 2; kf++)
#pragma unroll
            for (int mf = 0; mf < 4; mf++)
#pragma unroll
                for (int nf = 0; nf < 2; nf++)
                    acc[mf][nf] = __builtin_amdgcn_mfma_f32_16x16x32_bf16(bLo[nf * 2 + kf], aLo[mf * 2 + kf], acc[mf][nf], 0, 0, 0);
        __builtin_amdgcn_s_setprio(0);
        __builtin_amdgcn_sched_barrier(0);
        __builtin_amdgcn_s_barrier();

        // ---- phase 1: quad (mh0, nh1) ----
        if (pf) {
            async16(gA[2] + ko, lds + nxt + ldsoff[2]);
            async16(gA[3] + ko, lds + nxt + ldsoff[3]);
        }
#pragma unroll
        for (int nf = 0; nf < 2; nf++)
#pragma unroll
            for (int kf = 0; kf < 2; kf++)
                bHi[nf * 2 + kf] = *(const bf16x8*)(lds + cur + 32768 + ((wc * 4 + 2 + nf) * 2 + kf) * 1024 + lane * 16);
        __builtin_amdgcn_sched_barrier(0);
        __builtin_amdgcn_s_setprio(1);
#pragma unroll
        for (int kf = 0; kf < 2; kf++)
#pragma unroll
            for (int mf = 0; mf < 4; mf++)
#pragma unroll
                for (int nf = 0; nf < 2; nf++)
                    acc[mf][2 + nf] = __builtin_amdgcn_mfma_f32_16x16x32_bf16(bHi[nf * 2 + kf], aLo[mf * 2 + kf], acc[mf][2 + nf], 0, 0, 0);
        __builtin_amdgcn_s_setprio(0);
        __builtin_amdgcn_sched_barrier(0);
        __builtin_amdgcn_s_barrier();

        // ---- phase 2: quad (mh1, nh1) ----
        if (pf) {
            async16(gB[0] + ko, lds + nxt + 32768 + ldsoff[0]);
            async16(gB[1] + ko, lds + nxt + 32768 + ldsoff[1]);
        }
#pragma unroll
        for (int mf = 0; mf < 4; mf++)
#pragma unroll
            for (int kf = 0; kf < 2; kf++)
                aHi[mf * 2 + kf] = *(const bf16x8*)(lds + cur + ((wr * 8 + 4 + mf) * 2 + kf) * 1024 + lane * 16);
        __builtin_amdgcn_sched_barrier(0);
        __builtin_amdgcn_s_setprio(1);
#pragma unroll
        for (int kf = 0; kf < 2; kf++)
#pragma unroll
            for (int mf = 0; mf < 4; mf++)
#pragma unroll
                for (int nf = 0; nf < 2; nf++)
                    acc[4 + mf][2 + nf] = __builtin_amdgcn_mfma_f32_16x16x32_bf16(bHi[nf * 2 + kf], aHi[mf * 2 + kf], acc[4 + mf][2 + nf], 0, 0, 0);
        __builtin_amdgcn_s_setprio(0);
        __builtin_amdgcn_sched_barrier(0);
        __builtin_amdgcn_s_barrier();

        // ---- phase 3: quad (mh1, nh0) ----
        if (pf) {
            async16(gB[2] + ko, lds + nxt + 32768 + ldsoff[2]);
            async16(gB[3] + ko, lds + nxt + 32768 + ldsoff[3]);
        }
        __builtin_amdgcn_sched_barrier(0);
        __builtin_amdgcn_s_setprio(1);
#pragma unroll
        for (int kf = 0; kf < 2; kf++)
#pragma unroll
            for (int mf = 0; mf < 4; mf++)
#pragma unroll
                for (int nf = 0; nf < 2; nf++)
                    acc[4 + mf][nf] = __builtin_amdgcn_mfma_f32_16x16x32_bf16(bLo[nf * 2 + kf], aHi[mf * 2 + kf], acc[4 + mf][nf], 0, 0, 0);
        __builtin_amdgcn_s_setprio(0);
        __builtin_amdgcn_sched_barrier(0);
        __builtin_amdgcn_s_barrier();
    }

    // epilogue (transposed acc): row = M from lr, 4 contiguous N-cols from lh*4
#pragma unroll
    for (int nf = 0; nf < 4; nf++) {
        int col = n0 + wc * 64 + nf * 16 + lh * 4;
        float4 sc = *(const float4*)&scale[col];
        float4 sh = *(const float4*)&shift[col];
#pragma unroll
        for (int mf = 0; mf < 8; mf++) {
            int row = tile_m + wr * 128 + mf * 16 + lr;
            float y0 = acc[mf][nf][0] * sc.x + sh.x;
            float y1 = acc[mf][nf][1] * sc.y + sh.y;
            float y2 = acc[mf][nf][2] * sc.z + sh.z;
            float y3 = acc[mf][nf][3] * sc.w + sh.w;
            if (RELU) {
                y0 = fmaxf(y0, 0.f); y1 = fmaxf(y1, 0.f);
                y2 = fmaxf(y2, 0.f); y3 = fmaxf(y3, 0.f);
            }
            ushort4 pk;
            pk.x = f2bf(y0); pk.y = f2bf(y1); pk.z = f2bf(y2); pk.w = f2bf(y3);
            *(ushort4*)(out + (size_t)row * HID + col) = pk;
        }
    }
}

// ---------------- pooling + merged tail ----------------

__global__ void k_pool(const unsigned short* __restrict__ x, const int* __restrict__ bounds,
                       float* __restrict__ pooled) {
    int g = blockIdx.x, s = blockIdx.y, t = threadIdx.x; // 512 thr
    int b0 = bounds[g], b1 = bounds[g + 1];
    int len = b1 - b0;
    int r0 = b0 + (int)((long long)len * s / 8);
    int r1 = b0 + (int)((long long)len * (s + 1) / 8);
    float acc = 0.f;
    for (int r = r0; r < r1; r++) acc += bf2f(x[(size_t)r * HID + t]);
    if (r1 > r0) atomicAdd(&pooled[g * HID + t], acc);
}

// merged tail: mean -> @W1*s+sh -> @lin_w+lin_b -> gelu -> @clf_w+clf_b
__global__ void k_tail(const float* __restrict__ pooledSum, const int* __restrict__ bounds,
                       const float* __restrict__ W1, const float* __restrict__ scale,
                       const float* __restrict__ shift,
                       const float* __restrict__ lin_w, const float* __restrict__ lin_b,
                       const float* __restrict__ clf_w, const float* __restrict__ clf_b,
                       float* __restrict__ out) {
    int g = blockIdx.x, t = threadIdx.x; // 64 blocks x 512 thr
    __shared__ float r0[HID], r1[HID], r2[HID];
    int cnt = bounds[g + 1] - bounds[g];
    float invc = 1.f / fmaxf((float)cnt, 1.f);
    r0[t] = pooledSum[g * HID + t] * invc;
    __syncthreads();
    {
        float acc = 0.f;
        for (int k = 0; k < HID; k++) acc += r0[k] * W1[(size_t)k * HID + t];
        r1[t] = acc * scale[t] + shift[t];
    }
    __syncthreads();
    {
        float acc = lin_b[t];
        for (int k = 0; k < HID; k++) acc += r1[k] * lin_w[(size_t)k * HID + t];
        r2[t] = 0.5f * acc * (1.f + erff(acc * 0.7071067811865475f));
    }
    __syncthreads();
    if (t < COUT) {
        float acc = clf_b[t];
        for (int k = 0; k < HID; k++) acc += r2[k] * clf_w[(size_t)k * COUT + t];
        out[g * COUT + t] = acc;
    }
}

// ---------------- launch ----------------

extern "C" void kernel_launch(void* const* d_in, const int* in_sizes, int n_in,
                              void* d_out, int out_size, void* d_ws, size_t ws_size,
                              hipStream_t stream) {
    const float* x_f32   = (const float*)d_in[0];
    const int*   ei      = (const int*)d_in[1];
    const int*   batch   = (const int*)d_in[2];
    const float* enc_w   = (const float*)d_in[3];
    const float* enc_b   = (const float*)d_in[4];
    const float* conv_w0 = (const float*)d_in[5];
    const float* conv_b0 = (const float*)d_in[6];
    const float* bn0_g   = (const float*)d_in[7];
    const float* bn0_b   = (const float*)d_in[8];
    const float* conv_w1 = (const float*)d_in[9];
    const float* conv_b1 = (const float*)d_in[10];
    const float* bn1_g   = (const float*)d_in[11];
    const float* bn1_b   = (const float*)d_in[12];
    const float* lin_w   = (const float*)d_in[13];
    const float* lin_b   = (const float*)d_in[14];
    const float* clf_w   = (const float*)d_in[15];
    const float* clf_b   = (const float*)d_in[16];
    const int* srcp = ei;
    const int* dstp = ei + NE;

    char* ws = (char*)d_ws;
    size_t o = 0;
    auto alloc = [&](size_t b) { size_t r = o; o += (b + 255) & ~(size_t)255; return r; };
    unsigned short* buf0 = (unsigned short*)(ws + alloc((size_t)M_PAD * HID * 2));
    unsigned short* buf1 = (unsigned short*)(ws + alloc((size_t)M_PAD * HID * 2));
    unsigned short* buf2 = (unsigned short*)(ws + alloc((size_t)M_PAD * HID * 2));
    unsigned short* xbf  = buf0;  // alias: raw bf16 feats [NN][256]; dead after k_aggregate0
    unsigned short* zbuf = buf2;  // alias: agg0 output [M_PAD][320]; dead after l0 GEMM
    unsigned short* WfT  = (unsigned short*)(ws + alloc((size_t)HID * KF * 2));
    unsigned short* c0T  = (unsigned short*)(ws + alloc((size_t)HID * HID * 2)); // conv_w0[1]^T
    unsigned short* c1T  = (unsigned short*)(ws + alloc((size_t)HID * HID * 2)); // conv_w1[0]^T
    float* aff_scale = (float*)(ws + alloc(5 * HID * 4));
    float* aff_shift = (float*)(ws + alloc(5 * HID * 4));
    int* indeg  = (int*)(ws + alloc((size_t)NN * 4));
    int* off    = (int*)(ws + alloc((size_t)(NN + 1) * 4));
    int* cursor = (int*)(ws + alloc((size_t)NN * 4));
    int* csr    = (int*)(ws + alloc((size_t)NE * 4));
    int* scan_local = (int*)(ws + alloc((size_t)NN * 4));
    int* scan_bsum  = (int*)(ws + alloc((size_t)256 * 4));
    int* bounds = (int*)(ws + alloc((size_t)(NG + 1) * 4));
    float* pooledSum = (float*)(ws + alloc((size_t)NG * HID * 4));
    (void)ws_size; (void)n_in; (void)in_sizes; (void)out_size;

    hipMemsetAsync(indeg, 0, (size_t)NN * 4, stream);
    hipMemsetAsync(pooledSum, 0, (size_t)NG * HID * 4, stream);

    // prep (merged): cvt + hist | fused W | transposes | affine+bounds
    k_prep0<<<CVT_NB + HIST_NB, 256, 0, stream>>>(x_f32, xbf, dstp, indeg);
    k_fuse_w0<<<HID, 256, 0, stream>>>(enc_w, enc_b, conv_w0, WfT);
    k_transpose2<<<dim3(16, 16, 2), 256, 0, stream>>>(conv_w0 + HID * HID, conv_w1, c0T, c1T);
    k_affine_bounds<<<1, 512, 0, stream>>>(enc_b, conv_b0, bn0_g, bn0_b, conv_b1, bn1_g, bn1_b,
                                           aff_scale, aff_shift, batch, bounds);

    // CSR (2-kernel scan)
    k_scan1<<<SCAN_NB, 256, 0, stream>>>(indeg, scan_local, scan_bsum, NN);
    k_scan3<<<SCAN_NB, 256, 0, stream>>>(scan_local, scan_bsum, indeg, off, cursor, NN);
    k_fill<<<HIST_NB, 256, 0, stream>>>(srcp, dstp, cursor, csr, NE);

    // layer 0 (folded): agg raw 256-dim feats (+deg col) -> K=320 GEMM -> K=512 GEMM
    k_aggregate0<<<(NN * 64) / 256, 256, 0, stream>>>(xbf, off, csr, zbuf);
    k_gemm<1, KF / 64><<<GEMM_NWG, 512, 0, stream>>>(zbuf, WfT,
                                                     aff_scale + 1 * HID, aff_shift + 1 * HID, buf0);
    k_gemm<1, HID / 64><<<GEMM_NWG, 512, 0, stream>>>(buf0, c1T,
                                                      aff_scale + 2 * HID, aff_shift + 2 * HID, buf2);

    // layer 1: agg -> GEMM (bn0[1]+relu); final GEMM folded into tail
    k_aggregate<<<(NN * 64) / 256, 256, 0, stream>>>(buf2, off, csr, buf1);
    k_gemm<1, HID / 64><<<GEMM_NWG, 512, 0, stream>>>(buf1, c0T,
                                                      aff_scale + 3 * HID, aff_shift + 3 * HID, buf2);

    // tail: pool h1, then one merged kernel (mean -> W1+bn -> lin+gelu -> clf)
    k_pool<<<dim3(NG, 8), 512, 0, stream>>>(buf2, bounds, pooledSum);
    k_tail<<<NG, 512, 0, stream>>>(pooledSum, bounds, conv_w1 + HID * HID,
                                   aff_scale + 4 * HID, aff_shift + 4 * HID,
                                   lin_w, lin_b, clf_w, clf_b, (float*)d_out);
}